// Round 7
// baseline (234.207 us; speedup 1.0000x reference)
//
#include <hip/hip_runtime.h>
#include <math.h>

typedef __attribute__((ext_vector_type(8))) short short8;
typedef __attribute__((ext_vector_type(4))) float f32x4;
typedef __attribute__((ext_vector_type(4))) unsigned short us4;

constexpr int NB = 16, NS = 512, NT = 4096, IND0 = 512;

__device__ __forceinline__ unsigned short f2bf(float f) {
    __bf16 h = (__bf16)f;
    return __builtin_bit_cast(unsigned short, h);
}
__device__ __forceinline__ float bf2f(unsigned short h) {
    return __uint_as_float(((unsigned)h) << 16);
}

// ---------------------------------------------------------------------------
// Merged prep kernel, dispatched by block range:
//  [0,16)      : per-batch cumsum + frame->phoneme idx table
//  [16,2064)   : emb f32 -> bf16 cast
//  [2064,3600) : wprep dp_w1 -> Bs1   (IND=512)
//  [3600,4368) : wprep dp_w2 -> Bs2   (IND=256)
//  [4368,5904) : wprep f0_w1 -> Bsf   (IND=512)
__device__ __forceinline__ void wprep_one(const float* __restrict__ src,
                                          unsigned short* __restrict__ dst,
                                          int idx, int LOGIND) {
    int IND = 1 << LOGIND;
    int e  = idx & 7;
    int l  = (idx >> 3) & 63;
    int s  = (idx >> 9) & 1;
    int nf = (idx >> 10) & 3;
    int w  = (idx >> 12) & 3;
    int st = idx >> 14;
    int k   = st * 64 + s * 32 + ((l >> 4) << 3) + e;
    int col = w * 64 + nf * 16 + (l & 15);
    int i   = k & (IND - 1);
    int ko  = k >> LOGIND;
    dst[idx] = f2bf(src[(col * IND + i) * 3 + ko]);
}

__global__ __launch_bounds__(256)
void prep_kernel(const float* __restrict__ emb, const int* __restrict__ dur,
                 const float* __restrict__ dp_w1, const float* __restrict__ dp_w2,
                 const float* __restrict__ f0_w1,
                 unsigned short* __restrict__ emb_bf, int* __restrict__ idxarr,
                 unsigned short* __restrict__ Bs1, unsigned short* __restrict__ Bs2,
                 unsigned short* __restrict__ Bsf) {
    __shared__ int cs[NS];
    __shared__ int wsum[4];
    const int bid = blockIdx.x, t = threadIdx.x;
    if (bid < 16) {
        // --- cumsum + idx table ---
        int b = bid, w = t >> 6, lane = t & 63;
        int v0 = dur[b * NS + t * 2], v1 = dur[b * NS + t * 2 + 1];
        int incl = v0 + v1;
        for (int off = 1; off < 64; off <<= 1) {
            int n = __shfl_up(incl, off, 64);
            if (lane >= off) incl += n;
        }
        if (lane == 63) wsum[w] = incl;
        __syncthreads();
        int pre = 0;
        #pragma unroll
        for (int i = 0; i < 4; ++i) if (i < w) pre += wsum[i];
        incl += pre;
        cs[t * 2] = incl - v1;
        cs[t * 2 + 1] = incl;
        __syncthreads();
        int total = cs[NS - 1];
        for (int f = t; f < NT; f += 256) {
            int lo = 0, hi = NS;
            while (lo < hi) {
                int mid = (lo + hi) >> 1;
                if (cs[mid] <= f) lo = mid + 1; else hi = mid;
            }
            idxarr[b * NT + f] = (f < total) ? (lo < NS ? lo : NS - 1) : -1;
        }
    } else if (bid < 2064) {
        int i = (bid - 16) * 256 + t;   // short8 index; total 524288
        const float4* p = (const float4*)(emb + (size_t)i * 8);
        float4 v0 = p[0], v1 = p[1];
        short8 o;
        o[0] = (short)f2bf(v0.x); o[1] = (short)f2bf(v0.y);
        o[2] = (short)f2bf(v0.z); o[3] = (short)f2bf(v0.w);
        o[4] = (short)f2bf(v1.x); o[5] = (short)f2bf(v1.y);
        o[6] = (short)f2bf(v1.z); o[7] = (short)f2bf(v1.w);
        *(short8*)(emb_bf + (size_t)i * 8) = o;
    } else if (bid < 3600) {
        wprep_one(dp_w1, Bs1, (bid - 2064) * 256 + t, 9);
    } else if (bid < 4368) {
        wprep_one(dp_w2, Bs2, (bid - 3600) * 256 + t, 8);
    } else {
        wprep_one(f0_w1, Bsf, (bid - 4368) * 256 + t, 9);
    }
}

// ---------------------------------------------------------------------------
// Fused conv1d(k=3,pad=1)+bias+relu+LayerNorm(256) [+1x1 head], bf16 MFMA.
// Block: BM x 256, 4 waves (wave tile BM x 64), BK=64, A LDS double-buffer
// (XOR-16B swizzle), B single register buffer loaded straight from
// pre-swizzled global (no LDS). Per-thread rid[3] hoists all row-index /
// gather lookups out of the K loop. One __syncthreads per K step.
// BM=32 -> small blocks, high occupancy (latency hiding via TLP).
// GATHER=1: rows via idxarr + fused f32 `up` write during ko==1 steps.
// FIN: 0 = bf16 hout; 1 = dur head exp/max1; 2 = f0 head.
template<int GATHER, int BM, int IND, int FIN, int LOGSL>
__global__ __launch_bounds__(256, 6)
void conv_mfma(const unsigned short* __restrict__ src,
               const int* __restrict__ idxarr,
               const unsigned short* __restrict__ Bs,
               const float* __restrict__ bias, const float* __restrict__ gamma,
               const float* __restrict__ beta, unsigned short* __restrict__ hout,
               const float* __restrict__ wfin, const float* __restrict__ bfin,
               float* __restrict__ fout, float* __restrict__ up) {
    constexpr int K = 3 * IND;
    constexpr int NSTEP = K / 64;               // 24 or 12
    constexpr int KOSH = (IND == 512) ? 3 : 2;  // st -> ko shift
    constexpr int KOM = (IND / 64) - 1;
    constexpr int SL = 1 << LOGSL;
    constexpr int TPR = 256 / BM;               // threads per staged row
    constexpr int CH  = 8 / TPR;                // 16B chunks per thread
    constexpr int MF  = BM / 16;
    constexpr int BUFS = BM * 64;               // ushorts per A buffer

    __shared__ unsigned short smem[BM * 256];   // union: 2 A-bufs | H tile

    const int t = threadIdx.x;
    const int m0 = blockIdx.x * BM;
    const int w = t >> 6, l = t & 63, llo = l & 15, lhi = l >> 4;

    const int arow = t / TPR, sub = t % TPR;
    const int am = m0 + arow, ab = am >> LOGSL, as_ = am & (SL - 1);

    // Hoisted per-tap source rows (or -1 = zero pad)
    int rid[3];
    #pragma unroll
    for (int ko = 0; ko < 3; ++ko) {
        int tr = as_ + ko - 1;
        int r = -1;
        if (tr >= 0 && tr < SL) {
            if (GATHER) {
                int ix = idxarr[(ab << LOGSL) + tr];
                if (ix >= 0) r = ab * NS + ix;
            } else {
                r = ab * SL + tr;
            }
        }
        rid[ko] = r;
    }

    f32x4 acc[MF][4];
    #pragma unroll
    for (int i = 0; i < MF; ++i)
        #pragma unroll
        for (int j = 0; j < 4; ++j) acc[i][j] = (f32x4){0.f, 0.f, 0.f, 0.f};

    short8 a[CH];
    short8 b[8];

    auto stageA = [&](int st) {
        int ko = st >> KOSH;
        int i0 = (st & KOM) << 6;
        int r = rid[ko];
        if (r >= 0) {
            const unsigned short* p = src + (size_t)r * IND + i0 + sub * CH * 8;
            #pragma unroll
            for (int j = 0; j < CH; ++j) a[j] = *(const short8*)(p + j * 8);
        } else {
            #pragma unroll
            for (int j = 0; j < CH; ++j) a[j] = short8{0,0,0,0,0,0,0,0};
        }
    };
    auto dsWriteA = [&](int st) {
        int buf = (st & 1) * BUFS;
        #pragma unroll
        for (int j = 0; j < CH; ++j)
            *(short8*)&smem[buf + arow * 64 + (((sub * CH + j) ^ (arow & 7)) << 3)] = a[j];
        if (GATHER && (st >> KOSH) == 1) {  // staged rows == `up` rows
            int i0 = (st & KOM) << 6;
            float* dstp = up + (size_t)am * IND0 + i0 + sub * CH * 8;
            #pragma unroll
            for (int j = 0; j < CH; ++j) {
                f32x4 lo, hi;
                #pragma unroll
                for (int e = 0; e < 4; ++e) {
                    lo[e] = bf2f((unsigned short)a[j][e]);
                    hi[e] = bf2f((unsigned short)a[j][4 + e]);
                }
                *(f32x4*)(dstp + j * 8) = lo;
                *(f32x4*)(dstp + j * 8 + 4) = hi;
            }
        }
    };
    auto loadB = [&](int st) {
        const unsigned short* base = Bs + ((size_t)(st * 4 + w) * 8) * 512 + l * 8;
        #pragma unroll
        for (int s = 0; s < 2; ++s)
            #pragma unroll
            for (int nf = 0; nf < 4; ++nf)
                b[s * 4 + nf] = *(const short8*)(base + (nf * 2 + s) * 512);
    };
    auto mfmaPhase = [&](int buf) {
        #pragma unroll
        for (int s = 0; s < 2; ++s)
            #pragma unroll
            for (int mf = 0; mf < MF; ++mf) {
                int row = mf * 16 + llo;
                short8 af = *(const short8*)&smem[buf + row * 64 +
                                                 ((((s << 2) | lhi) ^ (row & 7)) << 3)];
                #pragma unroll
                for (int nf = 0; nf < 4; ++nf)
                    acc[mf][nf] = __builtin_amdgcn_mfma_f32_16x16x32_bf16(
                        af, b[s * 4 + nf], acc[mf][nf], 0, 0, 0);
            }
    };

    // --- K loop: A dbuf with 1 barrier/step, B single reg buffer ---
    stageA(0);
    dsWriteA(0);
    stageA(1);
    __syncthreads();
    for (int st = 0; st < NSTEP; ++st) {
        loadB(st);
        if (st + 1 < NSTEP) dsWriteA(st + 1);
        if (st + 2 < NSTEP) stageA(st + 2);
        mfmaPhase((st & 1) * BUFS);
        __syncthreads();
    }

    // --- epilogue: bias+relu -> H tile (XOR-swizzled), LN, emit ---
    unsigned short* H = smem;
    #pragma unroll
    for (int nf = 0; nf < 4; ++nf) {
        int col = w * 64 + nf * 16 + llo;
        float bv = bias[col];
        #pragma unroll
        for (int mf = 0; mf < MF; ++mf)
            #pragma unroll
            for (int r = 0; r < 4; ++r) {
                int row = mf * 16 + lhi * 4 + r;
                float v = acc[mf][nf][r] + bv;
                v = v > 0.f ? v : 0.f;
                H[row * 256 + ((((col >> 2) ^ (row & 15)) << 2) | (col & 3))] = f2bf(v);
            }
    }
    __syncthreads();

    constexpr int Q = 256 / BM;   // threads per row
    constexpr int NG = 64 / Q;    // 4-col groups per thread
    int row = t / Q, jj = t % Q;
    const unsigned short* Hr = H + row * 256;
    int rx = row & 15;
    float sum = 0.f, sq = 0.f;
    #pragma unroll
    for (int c4 = 0; c4 < NG; ++c4) {
        int g = jj * NG + c4;
        us4 hv = *(const us4*)&Hr[(g ^ rx) << 2];
        #pragma unroll
        for (int e = 0; e < 4; ++e) { float f = bf2f(hv[e]); sum += f; sq += f * f; }
    }
    #pragma unroll
    for (int off = Q / 2; off >= 1; off >>= 1) {
        sum += __shfl_xor(sum, off);
        sq  += __shfl_xor(sq, off);
    }
    float mean = sum * (1.f / 256.f);
    float var  = sq * (1.f / 256.f) - mean * mean;
    float rs   = rsqrtf(var + 1e-5f);
    int m = m0 + row;

    if (FIN == 0) {
        #pragma unroll
        for (int c4 = 0; c4 < NG; ++c4) {
            int g = jj * NG + c4;
            us4 hv = *(const us4*)&Hr[(g ^ rx) << 2];
            float4 gv = *(const float4*)&gamma[g * 4];
            float4 bv = *(const float4*)&beta[g * 4];
            us4 ov;
            ov[0] = f2bf((bf2f(hv[0]) - mean) * rs * gv.x + bv.x);
            ov[1] = f2bf((bf2f(hv[1]) - mean) * rs * gv.y + bv.y);
            ov[2] = f2bf((bf2f(hv[2]) - mean) * rs * gv.z + bv.z);
            ov[3] = f2bf((bf2f(hv[3]) - mean) * rs * gv.w + bv.w);
            *(us4*)&hout[(size_t)m * 256 + g * 4] = ov;
        }
    } else {
        float part = 0.f;
        #pragma unroll
        for (int c4 = 0; c4 < NG; ++c4) {
            int g = jj * NG + c4;
            us4 hv = *(const us4*)&Hr[(g ^ rx) << 2];
            float4 gv = *(const float4*)&gamma[g * 4];
            float4 bv = *(const float4*)&beta[g * 4];
            float4 wv = *(const float4*)&wfin[g * 4];
            part += ((bf2f(hv[0]) - mean) * rs * gv.x + bv.x) * wv.x;
            part += ((bf2f(hv[1]) - mean) * rs * gv.y + bv.y) * wv.y;
            part += ((bf2f(hv[2]) - mean) * rs * gv.z + bv.z) * wv.z;
            part += ((bf2f(hv[3]) - mean) * rs * gv.w + bv.w) * wv.w;
        }
        #pragma unroll
        for (int off = Q / 2; off >= 1; off >>= 1) part += __shfl_xor(part, off);
        if (jj == 0) {
            float r = part + bfin[0];
            if (FIN == 1) { r = expf(r); r = r > 1.f ? r : 1.f; }
            fout[m] = r;
        }
    }
}

// ---------------------------------------------------------------------------
extern "C" void kernel_launch(void* const* d_in, const int* in_sizes, int n_in,
                              void* d_out, int out_size, void* d_ws, size_t ws_size,
                              hipStream_t stream) {
    const float* emb    = (const float*)d_in[0];
    const int*   dur    = (const int*)  d_in[1];
    const float* dp_w1  = (const float*)d_in[2];
    const float* dp_b1  = (const float*)d_in[3];
    const float* dp_g1  = (const float*)d_in[4];
    const float* dp_be1 = (const float*)d_in[5];
    const float* dp_w2  = (const float*)d_in[6];
    const float* dp_b2  = (const float*)d_in[7];
    const float* dp_g2  = (const float*)d_in[8];
    const float* dp_be2 = (const float*)d_in[9];
    const float* dp_w3  = (const float*)d_in[10];
    const float* dp_b3  = (const float*)d_in[11];
    const float* f0_w1  = (const float*)d_in[12];
    const float* f0_b1  = (const float*)d_in[13];
    const float* f0_g1  = (const float*)d_in[14];
    const float* f0_be1 = (const float*)d_in[15];
    const float* f0_w2  = (const float*)d_in[16];
    const float* f0_b2  = (const float*)d_in[17];

    float* up   = (float*)d_out;                       // (16, 4096, 512)
    float* pdur = up + (size_t)NB * NT * IND0;         // (16, 512)
    float* pf0  = pdur + NB * NS;                      // (16, 4096)

    char* ws = (char*)d_ws;
    int*            idxarr = (int*)(ws);                          // 256 KB
    unsigned short* Bs1    = (unsigned short*)(ws + 262656);      // 768 KB
    unsigned short* Bs2    = (unsigned short*)(ws + 1049088);     // 384 KB
    unsigned short* Bsf    = (unsigned short*)(ws + 1442304);     // 768 KB
    unsigned short* h1     = (unsigned short*)(ws + 2228736);     // 4 MB
    unsigned short* emb_bf = (unsigned short*)(ws + 6423040);     // 8 MB

    prep_kernel<<<5904, 256, 0, stream>>>(emb, dur, dp_w1, dp_w2, f0_w1,
                                          emb_bf, idxarr, Bs1, Bs2, Bsf);

    // duration predictor conv1: emb_bf -> h1 (bf16)
    conv_mfma<0, 32, 512, 0, 9><<<NB * NS / 32, 256, 0, stream>>>(
        emb_bf, nullptr, Bs1, dp_b1, dp_g1, dp_be1, h1, nullptr, nullptr,
        nullptr, nullptr);
    // duration predictor conv2 + dur head: h1 -> pdur
    conv_mfma<0, 32, 256, 1, 9><<<NB * NS / 32, 256, 0, stream>>>(
        h1, nullptr, Bs2, dp_b2, dp_g2, dp_be2, nullptr, dp_w3, dp_b3,
        pdur, nullptr);
    // f0 conv + head: gather emb_bf rows via idxarr -> pf0, fused `up` write
    conv_mfma<1, 32, 512, 2, 12><<<NB * NT / 32, 256, 0, stream>>>(
        emb_bf, idxarr, Bsf, f0_b1, f0_g1, f0_be1, nullptr, f0_w2, f0_b2,
        pf0, up);
}

// Round 8
// 165.953 us; speedup vs baseline: 1.4113x; 1.4113x over previous
//
#include <hip/hip_runtime.h>
#include <math.h>

typedef __attribute__((ext_vector_type(8))) short short8;
typedef __attribute__((ext_vector_type(4))) float f32x4;
typedef __attribute__((ext_vector_type(4))) unsigned short us4;

constexpr int NB = 16, NS = 512, NT = 4096, IND0 = 512;

__device__ __forceinline__ unsigned short f2bf(float f) {
    __bf16 h = (__bf16)f;
    return __builtin_bit_cast(unsigned short, h);
}
__device__ __forceinline__ float bf2f(unsigned short h) {
    return __uint_as_float(((unsigned)h) << 16);
}

// ---------------------------------------------------------------------------
// Merged prep kernel, dispatched by block range:
//  [0,16)      : per-batch cumsum + frame->phoneme idx table
//  [16,2064)   : emb f32 -> bf16 cast
//  [2064,3600) : wprep dp_w1 -> Bs1   (IND=512)
//  [3600,4368) : wprep dp_w2 -> Bs2   (IND=256)
//  [4368,5904) : wprep f0_w1 -> Bsf   (IND=512)
__device__ __forceinline__ void wprep_one(const float* __restrict__ src,
                                          unsigned short* __restrict__ dst,
                                          int idx, int LOGIND) {
    int IND = 1 << LOGIND;
    int e  = idx & 7;
    int l  = (idx >> 3) & 63;
    int s  = (idx >> 9) & 1;
    int nf = (idx >> 10) & 3;
    int w  = (idx >> 12) & 3;
    int st = idx >> 14;
    int k   = st * 64 + s * 32 + ((l >> 4) << 3) + e;
    int col = w * 64 + nf * 16 + (l & 15);
    int i   = k & (IND - 1);
    int ko  = k >> LOGIND;
    dst[idx] = f2bf(src[(col * IND + i) * 3 + ko]);
}

__global__ __launch_bounds__(256)
void prep_kernel(const float* __restrict__ emb, const int* __restrict__ dur,
                 const float* __restrict__ dp_w1, const float* __restrict__ dp_w2,
                 const float* __restrict__ f0_w1,
                 unsigned short* __restrict__ emb_bf, int* __restrict__ idxarr,
                 unsigned short* __restrict__ Bs1, unsigned short* __restrict__ Bs2,
                 unsigned short* __restrict__ Bsf) {
    __shared__ int cs[NS];
    __shared__ int wsum[4];
    const int bid = blockIdx.x, t = threadIdx.x;
    if (bid < 16) {
        // --- cumsum + idx table ---
        int b = bid, w = t >> 6, lane = t & 63;
        int v0 = dur[b * NS + t * 2], v1 = dur[b * NS + t * 2 + 1];
        int incl = v0 + v1;
        for (int off = 1; off < 64; off <<= 1) {
            int n = __shfl_up(incl, off, 64);
            if (lane >= off) incl += n;
        }
        if (lane == 63) wsum[w] = incl;
        __syncthreads();
        int pre = 0;
        #pragma unroll
        for (int i = 0; i < 4; ++i) if (i < w) pre += wsum[i];
        incl += pre;
        cs[t * 2] = incl - v1;
        cs[t * 2 + 1] = incl;
        __syncthreads();
        int total = cs[NS - 1];
        for (int f = t; f < NT; f += 256) {
            int lo = 0, hi = NS;
            while (lo < hi) {
                int mid = (lo + hi) >> 1;
                if (cs[mid] <= f) lo = mid + 1; else hi = mid;
            }
            idxarr[b * NT + f] = (f < total) ? (lo < NS ? lo : NS - 1) : -1;
        }
    } else if (bid < 2064) {
        int i = (bid - 16) * 256 + t;   // short8 index; total 524288
        const float4* p = (const float4*)(emb + (size_t)i * 8);
        float4 v0 = p[0], v1 = p[1];
        short8 o;
        o[0] = (short)f2bf(v0.x); o[1] = (short)f2bf(v0.y);
        o[2] = (short)f2bf(v0.z); o[3] = (short)f2bf(v0.w);
        o[4] = (short)f2bf(v1.x); o[5] = (short)f2bf(v1.y);
        o[6] = (short)f2bf(v1.z); o[7] = (short)f2bf(v1.w);
        *(short8*)(emb_bf + (size_t)i * 8) = o;
    } else if (bid < 3600) {
        wprep_one(dp_w1, Bs1, (bid - 2064) * 256 + t, 9);
    } else if (bid < 4368) {
        wprep_one(dp_w2, Bs2, (bid - 3600) * 256 + t, 8);
    } else {
        wprep_one(f0_w1, Bsf, (bid - 4368) * 256 + t, 9);
    }
}

// ---------------------------------------------------------------------------
// Fused conv1d(k=3,pad=1)+bias+relu+LayerNorm(256) [+1x1 head], bf16 MFMA.
// Block: BM x 256, 4 waves (wave tile BM x 64), BK=64, A LDS double-buffer
// (XOR-16B swizzle), B DOUBLE register buffer (b0/b1 ping-pong): loadB(st+1)
// issues a full step before mfmaPhase(st+1) consumes it, so the barrier
// drain overlaps B's L2 latency with the current MFMA phase. Per-thread
// rid[3] hoists gather lookups. One __syncthreads per K step.
// GATHER=1: rows via idxarr + fused f32 `up` write during ko==1 steps.
// FIN: 0 = bf16 hout; 1 = dur head exp/max1; 2 = f0 head.
template<int GATHER, int BM, int IND, int FIN, int LOGSL>
__global__ __launch_bounds__(256, (BM == 64 ? 3 : 4))
void conv_mfma(const unsigned short* __restrict__ src,
               const int* __restrict__ idxarr,
               const unsigned short* __restrict__ Bs,
               const float* __restrict__ bias, const float* __restrict__ gamma,
               const float* __restrict__ beta, unsigned short* __restrict__ hout,
               const float* __restrict__ wfin, const float* __restrict__ bfin,
               float* __restrict__ fout, float* __restrict__ up) {
    constexpr int K = 3 * IND;
    constexpr int NSTEP = K / 64;               // 24 or 12 (even)
    constexpr int KOSH = (IND == 512) ? 3 : 2;  // st -> ko shift
    constexpr int KOM = (IND / 64) - 1;
    constexpr int SL = 1 << LOGSL;
    constexpr int TPR = 256 / BM;               // threads per staged row
    constexpr int CH  = 8 / TPR;                // 16B chunks per thread
    constexpr int MF  = BM / 16;
    constexpr int BUFS = BM * 64;               // ushorts per A buffer

    __shared__ unsigned short smem[BM * 256];   // union: 2 A-bufs | H tile

    const int t = threadIdx.x;
    const int m0 = blockIdx.x * BM;
    const int w = t >> 6, l = t & 63, llo = l & 15, lhi = l >> 4;

    const int arow = t / TPR, sub = t % TPR;
    const int am = m0 + arow, ab = am >> LOGSL, as_ = am & (SL - 1);

    // Hoisted per-tap source rows (or -1 = zero pad)
    int rid[3];
    #pragma unroll
    for (int ko = 0; ko < 3; ++ko) {
        int tr = as_ + ko - 1;
        int r = -1;
        if (tr >= 0 && tr < SL) {
            if (GATHER) {
                int ix = idxarr[(ab << LOGSL) + tr];
                if (ix >= 0) r = ab * NS + ix;
            } else {
                r = ab * SL + tr;
            }
        }
        rid[ko] = r;
    }

    f32x4 acc[MF][4];
    #pragma unroll
    for (int i = 0; i < MF; ++i)
        #pragma unroll
        for (int j = 0; j < 4; ++j) acc[i][j] = (f32x4){0.f, 0.f, 0.f, 0.f};

    short8 a[CH];
    short8 b0[8], b1[8];

    auto stageA = [&](int st) {
        int ko = st >> KOSH;
        int i0 = (st & KOM) << 6;
        int r = rid[ko];
        if (r >= 0) {
            const unsigned short* p = src + (size_t)r * IND + i0 + sub * CH * 8;
            #pragma unroll
            for (int j = 0; j < CH; ++j) a[j] = *(const short8*)(p + j * 8);
        } else {
            #pragma unroll
            for (int j = 0; j < CH; ++j) a[j] = short8{0,0,0,0,0,0,0,0};
        }
    };
    auto dsWriteA = [&](int st) {
        int buf = (st & 1) * BUFS;
        #pragma unroll
        for (int j = 0; j < CH; ++j)
            *(short8*)&smem[buf + arow * 64 + (((sub * CH + j) ^ (arow & 7)) << 3)] = a[j];
        if (GATHER && (st >> KOSH) == 1) {  // staged rows == `up` rows
            int i0 = (st & KOM) << 6;
            float* dstp = up + (size_t)am * IND0 + i0 + sub * CH * 8;
            #pragma unroll
            for (int j = 0; j < CH; ++j) {
                f32x4 lo, hi;
                #pragma unroll
                for (int e = 0; e < 4; ++e) {
                    lo[e] = bf2f((unsigned short)a[j][e]);
                    hi[e] = bf2f((unsigned short)a[j][4 + e]);
                }
                *(f32x4*)(dstp + j * 8) = lo;
                *(f32x4*)(dstp + j * 8 + 4) = hi;
            }
        }
    };
    auto loadB = [&](int st, short8* b) {
        const unsigned short* base = Bs + ((size_t)(st * 4 + w) * 8) * 512 + l * 8;
        #pragma unroll
        for (int s = 0; s < 2; ++s)
            #pragma unroll
            for (int nf = 0; nf < 4; ++nf)
                b[s * 4 + nf] = *(const short8*)(base + (nf * 2 + s) * 512);
    };
    auto mfmaPhase = [&](int buf, short8* bc) {
        #pragma unroll
        for (int s = 0; s < 2; ++s)
            #pragma unroll
            for (int mf = 0; mf < MF; ++mf) {
                int row = mf * 16 + llo;
                short8 af = *(const short8*)&smem[buf + row * 64 +
                                                 ((((s << 2) | lhi) ^ (row & 7)) << 3)];
                #pragma unroll
                for (int nf = 0; nf < 4; ++nf)
                    acc[mf][nf] = __builtin_amdgcn_mfma_f32_16x16x32_bf16(
                        af, bc[s * 4 + nf], acc[mf][nf], 0, 0, 0);
            }
    };

    // --- K loop: A LDS dbuf + B reg dbuf, 1 barrier/step ---
    stageA(0);
    dsWriteA(0);
    stageA(1);
    loadB(0, b0);
    __syncthreads();
    for (int st = 0; st < NSTEP; st += 2) {
        // even step: consume b0, prefetch b1 for st+1
        loadB(st + 1, b1);
        dsWriteA(st + 1);
        if (st + 2 < NSTEP) stageA(st + 2);
        mfmaPhase(0, b0);
        __syncthreads();
        // odd step: consume b1, prefetch b0 for st+2
        if (st + 2 < NSTEP) {
            loadB(st + 2, b0);
            dsWriteA(st + 2);
        }
        if (st + 3 < NSTEP) stageA(st + 3);
        mfmaPhase(BUFS, b1);
        __syncthreads();
    }

    // --- epilogue: bias+relu -> H tile (XOR-swizzled), LN, emit ---
    unsigned short* H = smem;
    #pragma unroll
    for (int nf = 0; nf < 4; ++nf) {
        int col = w * 64 + nf * 16 + llo;
        float bv = bias[col];
        #pragma unroll
        for (int mf = 0; mf < MF; ++mf)
            #pragma unroll
            for (int r = 0; r < 4; ++r) {
                int row = mf * 16 + lhi * 4 + r;
                float v = acc[mf][nf][r] + bv;
                v = v > 0.f ? v : 0.f;
                H[row * 256 + ((((col >> 2) ^ (row & 15)) << 2) | (col & 3))] = f2bf(v);
            }
    }
    __syncthreads();

    constexpr int Q = 256 / BM;   // threads per row
    constexpr int NG = 64 / Q;    // 4-col groups per thread
    int row = t / Q, jj = t % Q;
    const unsigned short* Hr = H + row * 256;
    int rx = row & 15;
    float sum = 0.f, sq = 0.f;
    #pragma unroll
    for (int c4 = 0; c4 < NG; ++c4) {
        int g = jj * NG + c4;
        us4 hv = *(const us4*)&Hr[(g ^ rx) << 2];
        #pragma unroll
        for (int e = 0; e < 4; ++e) { float f = bf2f(hv[e]); sum += f; sq += f * f; }
    }
    #pragma unroll
    for (int off = Q / 2; off >= 1; off >>= 1) {
        sum += __shfl_xor(sum, off);
        sq  += __shfl_xor(sq, off);
    }
    float mean = sum * (1.f / 256.f);
    float var  = sq * (1.f / 256.f) - mean * mean;
    float rs   = rsqrtf(var + 1e-5f);
    int m = m0 + row;

    if (FIN == 0) {
        #pragma unroll
        for (int c4 = 0; c4 < NG; ++c4) {
            int g = jj * NG + c4;
            us4 hv = *(const us4*)&Hr[(g ^ rx) << 2];
            float4 gv = *(const float4*)&gamma[g * 4];
            float4 bv = *(const float4*)&beta[g * 4];
            us4 ov;
            ov[0] = f2bf((bf2f(hv[0]) - mean) * rs * gv.x + bv.x);
            ov[1] = f2bf((bf2f(hv[1]) - mean) * rs * gv.y + bv.y);
            ov[2] = f2bf((bf2f(hv[2]) - mean) * rs * gv.z + bv.z);
            ov[3] = f2bf((bf2f(hv[3]) - mean) * rs * gv.w + bv.w);
            *(us4*)&hout[(size_t)m * 256 + g * 4] = ov;
        }
    } else {
        float part = 0.f;
        #pragma unroll
        for (int c4 = 0; c4 < NG; ++c4) {
            int g = jj * NG + c4;
            us4 hv = *(const us4*)&Hr[(g ^ rx) << 2];
            float4 gv = *(const float4*)&gamma[g * 4];
            float4 bv = *(const float4*)&beta[g * 4];
            float4 wv = *(const float4*)&wfin[g * 4];
            part += ((bf2f(hv[0]) - mean) * rs * gv.x + bv.x) * wv.x;
            part += ((bf2f(hv[1]) - mean) * rs * gv.y + bv.y) * wv.y;
            part += ((bf2f(hv[2]) - mean) * rs * gv.z + bv.z) * wv.z;
            part += ((bf2f(hv[3]) - mean) * rs * gv.w + bv.w) * wv.w;
        }
        #pragma unroll
        for (int off = Q / 2; off >= 1; off >>= 1) part += __shfl_xor(part, off);
        if (jj == 0) {
            float r = part + bfin[0];
            if (FIN == 1) { r = expf(r); r = r > 1.f ? r : 1.f; }
            fout[m] = r;
        }
    }
}

// ---------------------------------------------------------------------------
extern "C" void kernel_launch(void* const* d_in, const int* in_sizes, int n_in,
                              void* d_out, int out_size, void* d_ws, size_t ws_size,
                              hipStream_t stream) {
    const float* emb    = (const float*)d_in[0];
    const int*   dur    = (const int*)  d_in[1];
    const float* dp_w1  = (const float*)d_in[2];
    const float* dp_b1  = (const float*)d_in[3];
    const float* dp_g1  = (const float*)d_in[4];
    const float* dp_be1 = (const float*)d_in[5];
    const float* dp_w2  = (const float*)d_in[6];
    const float* dp_b2  = (const float*)d_in[7];
    const float* dp_g2  = (const float*)d_in[8];
    const float* dp_be2 = (const float*)d_in[9];
    const float* dp_w3  = (const float*)d_in[10];
    const float* dp_b3  = (const float*)d_in[11];
    const float* f0_w1  = (const float*)d_in[12];
    const float* f0_b1  = (const float*)d_in[13];
    const float* f0_g1  = (const float*)d_in[14];
    const float* f0_be1 = (const float*)d_in[15];
    const float* f0_w2  = (const float*)d_in[16];
    const float* f0_b2  = (const float*)d_in[17];

    float* up   = (float*)d_out;                       // (16, 4096, 512)
    float* pdur = up + (size_t)NB * NT * IND0;         // (16, 512)
    float* pf0  = pdur + NB * NS;                      // (16, 4096)

    char* ws = (char*)d_ws;
    int*            idxarr = (int*)(ws);                          // 256 KB
    unsigned short* Bs1    = (unsigned short*)(ws + 262656);      // 768 KB
    unsigned short* Bs2    = (unsigned short*)(ws + 1049088);     // 384 KB
    unsigned short* Bsf    = (unsigned short*)(ws + 1442304);     // 768 KB
    unsigned short* h1     = (unsigned short*)(ws + 2228736);     // 4 MB
    unsigned short* emb_bf = (unsigned short*)(ws + 6423040);     // 8 MB

    prep_kernel<<<5904, 256, 0, stream>>>(emb, dur, dp_w1, dp_w2, f0_w1,
                                          emb_bf, idxarr, Bs1, Bs2, Bsf);

    // duration predictor conv1: emb_bf -> h1 (bf16)
    conv_mfma<0, 32, 512, 0, 9><<<NB * NS / 32, 256, 0, stream>>>(
        emb_bf, nullptr, Bs1, dp_b1, dp_g1, dp_be1, h1, nullptr, nullptr,
        nullptr, nullptr);
    // duration predictor conv2 + dur head: h1 -> pdur
    conv_mfma<0, 32, 256, 1, 9><<<NB * NS / 32, 256, 0, stream>>>(
        h1, nullptr, Bs2, dp_b2, dp_g2, dp_be2, nullptr, dp_w3, dp_b3,
        pdur, nullptr);
    // f0 conv + head: gather emb_bf rows via idxarr -> pf0, fused `up` write
    conv_mfma<1, 64, 512, 2, 12><<<NB * NT / 64, 256, 0, stream>>>(
        emb_bf, idxarr, Bsf, f0_b1, f0_g1, f0_be1, nullptr, f0_w2, f0_b2,
        pf0, up);
}

// Round 9
// 150.642 us; speedup vs baseline: 1.5547x; 1.1016x over previous
//
#include <hip/hip_runtime.h>
#include <math.h>

typedef __attribute__((ext_vector_type(8))) short short8;
typedef __attribute__((ext_vector_type(4))) float f32x4;
typedef __attribute__((ext_vector_type(4))) unsigned short us4;

constexpr int NB = 16, NS = 512, NT = 4096, IND0 = 512;

__device__ __forceinline__ unsigned short f2bf(float f) {
    __bf16 h = (__bf16)f;
    return __builtin_bit_cast(unsigned short, h);
}
__device__ __forceinline__ float bf2f(unsigned short h) {
    return __uint_as_float(((unsigned)h) << 16);
}

// ---------------------------------------------------------------------------
// Merged prep kernel, dispatched by block range:
//  [0,16)      : per-batch cumsum + frame->phoneme idx table
//  [16,2064)   : emb f32 -> bf16 cast
//  [2064,3600) : wprep dp_w1 -> Bs1   (IND=512)
//  [3600,4368) : wprep dp_w2 -> Bs2   (IND=256)
//  [4368,5904) : wprep f0_w1 -> Bsf   (IND=512)
__device__ __forceinline__ void wprep_one(const float* __restrict__ src,
                                          unsigned short* __restrict__ dst,
                                          int idx, int LOGIND) {
    int IND = 1 << LOGIND;
    int e  = idx & 7;
    int l  = (idx >> 3) & 63;
    int s  = (idx >> 9) & 1;
    int nf = (idx >> 10) & 3;
    int w  = (idx >> 12) & 3;
    int st = idx >> 14;
    int k   = st * 64 + s * 32 + ((l >> 4) << 3) + e;
    int col = w * 64 + nf * 16 + (l & 15);
    int i   = k & (IND - 1);
    int ko  = k >> LOGIND;
    dst[idx] = f2bf(src[(col * IND + i) * 3 + ko]);
}

__global__ __launch_bounds__(256)
void prep_kernel(const float* __restrict__ emb, const int* __restrict__ dur,
                 const float* __restrict__ dp_w1, const float* __restrict__ dp_w2,
                 const float* __restrict__ f0_w1,
                 unsigned short* __restrict__ emb_bf, int* __restrict__ idxarr,
                 unsigned short* __restrict__ Bs1, unsigned short* __restrict__ Bs2,
                 unsigned short* __restrict__ Bsf) {
    __shared__ int cs[NS];
    __shared__ int wsum[4];
    const int bid = blockIdx.x, t = threadIdx.x;
    if (bid < 16) {
        // --- cumsum + idx table ---
        int b = bid, w = t >> 6, lane = t & 63;
        int v0 = dur[b * NS + t * 2], v1 = dur[b * NS + t * 2 + 1];
        int incl = v0 + v1;
        for (int off = 1; off < 64; off <<= 1) {
            int n = __shfl_up(incl, off, 64);
            if (lane >= off) incl += n;
        }
        if (lane == 63) wsum[w] = incl;
        __syncthreads();
        int pre = 0;
        #pragma unroll
        for (int i = 0; i < 4; ++i) if (i < w) pre += wsum[i];
        incl += pre;
        cs[t * 2] = incl - v1;
        cs[t * 2 + 1] = incl;
        __syncthreads();
        int total = cs[NS - 1];
        for (int f = t; f < NT; f += 256) {
            int lo = 0, hi = NS;
            while (lo < hi) {
                int mid = (lo + hi) >> 1;
                if (cs[mid] <= f) lo = mid + 1; else hi = mid;
            }
            idxarr[b * NT + f] = (f < total) ? (lo < NS ? lo : NS - 1) : -1;
        }
    } else if (bid < 2064) {
        int i = (bid - 16) * 256 + t;   // short8 index; total 524288
        const float4* p = (const float4*)(emb + (size_t)i * 8);
        float4 v0 = p[0], v1 = p[1];
        short8 o;
        o[0] = (short)f2bf(v0.x); o[1] = (short)f2bf(v0.y);
        o[2] = (short)f2bf(v0.z); o[3] = (short)f2bf(v0.w);
        o[4] = (short)f2bf(v1.x); o[5] = (short)f2bf(v1.y);
        o[6] = (short)f2bf(v1.z); o[7] = (short)f2bf(v1.w);
        *(short8*)(emb_bf + (size_t)i * 8) = o;
    } else if (bid < 3600) {
        wprep_one(dp_w1, Bs1, (bid - 2064) * 256 + t, 9);
    } else if (bid < 4368) {
        wprep_one(dp_w2, Bs2, (bid - 3600) * 256 + t, 8);
    } else {
        wprep_one(f0_w1, Bsf, (bid - 4368) * 256 + t, 9);
    }
}

// ---------------------------------------------------------------------------
// A-RESIDENT fused conv1d(k=3,pad=1)+bias+relu+LayerNorm(256) [+1x1 head].
// Key structure: the A-tile for the ENTIRE K=3*IND is just BM+2 gathered
// rows. Stage them into LDS once (XOR-16B chunk swizzle), sync once, then
// run a BARRIER-FREE K loop: ds_read A frags + B register ping-pong + MFMA.
// No vmcnt(0) drains in the loop; waves drift for phase diversity.
// GATHER=1: rows via idxarr; `up` (f32) written from staging registers.
// FIN: 0 = bf16 hout; 1 = dur head exp/max1; 2 = f0 head.
template<int GATHER, int BM, int IND, int FIN, int LOGSL>
__global__ __launch_bounds__(256, (BM == 32 ? 4 : 2))
void conv_mfma(const unsigned short* __restrict__ src,
               const int* __restrict__ idxarr,
               const unsigned short* __restrict__ Bs,
               const float* __restrict__ bias, const float* __restrict__ gamma,
               const float* __restrict__ beta, unsigned short* __restrict__ hout,
               const float* __restrict__ wfin, const float* __restrict__ bfin,
               float* __restrict__ fout, float* __restrict__ up) {
    constexpr int K = 3 * IND;
    constexpr int NSTEP = K / 64;               // 24 or 12 (even)
    constexpr int KOSH = (IND == 512) ? 3 : 2;  // st -> ko shift
    constexpr int KOM = (IND / 64) - 1;
    constexpr int SL = 1 << LOGSL;
    constexpr int MF = BM / 16;
    constexpr int CPR = IND / 8;                // 16B chunks per row
    constexpr int CPS = CPR / 4;                // chunks per (row, sub) visit

    // A row-table: (BM+2) rows x IND bf16, chunk-swizzled. Unions with H tile.
    __shared__ unsigned short smem[(BM + 2) * IND];

    const int t = threadIdx.x;
    const int m0 = blockIdx.x * BM;
    const int w = t >> 6, l = t & 63, llo = l & 15, lhi = l >> 4;
    const int ab = m0 >> LOGSL, as0 = m0 & (SL - 1);

    // --- one-time staging of the A row-table (+ fused `up` write) ---
    {
        int sub = t & 3;
        for (int j = t >> 2; j < BM + 2; j += 64) {
            int tr = as0 + j - 1;
            int r = -1;
            if (tr >= 0 && tr < SL) {
                if (GATHER) {
                    int ix = idxarr[(ab << LOGSL) + tr];
                    if (ix >= 0) r = ab * NS + ix;
                } else {
                    r = ab * SL + tr;
                }
            }
            const unsigned short* p =
                src + (size_t)(r >= 0 ? r : 0) * IND + sub * (IND / 4);
            #pragma unroll
            for (int c = 0; c < CPS; ++c) {
                short8 v = short8{0,0,0,0,0,0,0,0};
                if (r >= 0) v = *(const short8*)(p + c * 8);
                int ch = sub * CPS + c;
                *(short8*)&smem[j * IND + ((ch ^ (j & 7)) << 3)] = v;
                if (GATHER && j >= 1 && j < BM + 1) {
                    float* dstp = up + (size_t)(m0 + j - 1) * IND0
                                  + sub * (IND / 4) + c * 8;
                    f32x4 lo, hi;
                    #pragma unroll
                    for (int e = 0; e < 4; ++e) {
                        lo[e] = bf2f((unsigned short)v[e]);
                        hi[e] = bf2f((unsigned short)v[4 + e]);
                    }
                    *(f32x4*)dstp = lo;
                    *(f32x4*)(dstp + 4) = hi;
                }
            }
        }
    }
    __syncthreads();

    f32x4 acc[MF][4];
    #pragma unroll
    for (int i = 0; i < MF; ++i)
        #pragma unroll
        for (int j = 0; j < 4; ++j) acc[i][j] = (f32x4){0.f, 0.f, 0.f, 0.f};

    short8 b0[8], b1[8];

    auto loadB = [&](int st, short8* b) {
        const unsigned short* base = Bs + ((size_t)(st * 4 + w) * 8) * 512 + l * 8;
        #pragma unroll
        for (int s = 0; s < 2; ++s)
            #pragma unroll
            for (int nf = 0; nf < 4; ++nf)
                b[s * 4 + nf] = *(const short8*)(base + (nf * 2 + s) * 512);
    };
    auto mfmaPhase = [&](int st, short8* bc) {
        int ko = st >> KOSH;
        int cb = (st & KOM) << 3;               // chunk base within row
        #pragma unroll
        for (int s = 0; s < 2; ++s)
            #pragma unroll
            for (int mf = 0; mf < MF; ++mf) {
                int jr = mf * 16 + llo + ko;    // table row
                int ch = cb + ((s << 2) | lhi);
                short8 af = *(const short8*)&smem[jr * IND + ((ch ^ (jr & 7)) << 3)];
                #pragma unroll
                for (int nf = 0; nf < 4; ++nf)
                    acc[mf][nf] = __builtin_amdgcn_mfma_f32_16x16x32_bf16(
                        af, bc[s * 4 + nf], acc[mf][nf], 0, 0, 0);
            }
    };

    // --- BARRIER-FREE K loop: B reg ping-pong, A from resident LDS ---
    loadB(0, b0);
    for (int st = 0; st < NSTEP; st += 2) {
        loadB(st + 1, b1);
        mfmaPhase(st, b0);
        if (st + 2 < NSTEP) loadB(st + 2, b0);
        mfmaPhase(st + 1, b1);
    }
    __syncthreads();   // protect A-table before H-tile overwrite

    // --- epilogue: bias+relu -> H tile (XOR-swizzled), LN, emit ---
    unsigned short* H = smem;
    #pragma unroll
    for (int nf = 0; nf < 4; ++nf) {
        int col = w * 64 + nf * 16 + llo;
        float bv = bias[col];
        #pragma unroll
        for (int mf = 0; mf < MF; ++mf)
            #pragma unroll
            for (int r = 0; r < 4; ++r) {
                int row = mf * 16 + lhi * 4 + r;
                float v = acc[mf][nf][r] + bv;
                v = v > 0.f ? v : 0.f;
                H[row * 256 + ((((col >> 2) ^ (row & 15)) << 2) | (col & 3))] = f2bf(v);
            }
    }
    __syncthreads();

    constexpr int Q = 256 / BM;   // threads per row
    constexpr int NG = 64 / Q;    // 4-col groups per thread
    int row = t / Q, jj = t % Q;
    const unsigned short* Hr = H + row * 256;
    int rx = row & 15;
    float sum = 0.f, sq = 0.f;
    #pragma unroll
    for (int c4 = 0; c4 < NG; ++c4) {
        int g = jj * NG + c4;
        us4 hv = *(const us4*)&Hr[(g ^ rx) << 2];
        #pragma unroll
        for (int e = 0; e < 4; ++e) { float f = bf2f(hv[e]); sum += f; sq += f * f; }
    }
    #pragma unroll
    for (int off = Q / 2; off >= 1; off >>= 1) {
        sum += __shfl_xor(sum, off);
        sq  += __shfl_xor(sq, off);
    }
    float mean = sum * (1.f / 256.f);
    float var  = sq * (1.f / 256.f) - mean * mean;
    float rs   = rsqrtf(var + 1e-5f);
    int m = m0 + row;

    if (FIN == 0) {
        #pragma unroll
        for (int c4 = 0; c4 < NG; ++c4) {
            int g = jj * NG + c4;
            us4 hv = *(const us4*)&Hr[(g ^ rx) << 2];
            float4 gv = *(const float4*)&gamma[g * 4];
            float4 bv = *(const float4*)&beta[g * 4];
            us4 ov;
            ov[0] = f2bf((bf2f(hv[0]) - mean) * rs * gv.x + bv.x);
            ov[1] = f2bf((bf2f(hv[1]) - mean) * rs * gv.y + bv.y);
            ov[2] = f2bf((bf2f(hv[2]) - mean) * rs * gv.z + bv.z);
            ov[3] = f2bf((bf2f(hv[3]) - mean) * rs * gv.w + bv.w);
            *(us4*)&hout[(size_t)m * 256 + g * 4] = ov;
        }
    } else {
        float part = 0.f;
        #pragma unroll
        for (int c4 = 0; c4 < NG; ++c4) {
            int g = jj * NG + c4;
            us4 hv = *(const us4*)&Hr[(g ^ rx) << 2];
            float4 gv = *(const float4*)&gamma[g * 4];
            float4 bv = *(const float4*)&beta[g * 4];
            float4 wv = *(const float4*)&wfin[g * 4];
            part += ((bf2f(hv[0]) - mean) * rs * gv.x + bv.x) * wv.x;
            part += ((bf2f(hv[1]) - mean) * rs * gv.y + bv.y) * wv.y;
            part += ((bf2f(hv[2]) - mean) * rs * gv.z + bv.z) * wv.z;
            part += ((bf2f(hv[3]) - mean) * rs * gv.w + bv.w) * wv.w;
        }
        #pragma unroll
        for (int off = Q / 2; off >= 1; off >>= 1) part += __shfl_xor(part, off);
        if (jj == 0) {
            float r = part + bfin[0];
            if (FIN == 1) { r = expf(r); r = r > 1.f ? r : 1.f; }
            fout[m] = r;
        }
    }
}

// ---------------------------------------------------------------------------
extern "C" void kernel_launch(void* const* d_in, const int* in_sizes, int n_in,
                              void* d_out, int out_size, void* d_ws, size_t ws_size,
                              hipStream_t stream) {
    const float* emb    = (const float*)d_in[0];
    const int*   dur    = (const int*)  d_in[1];
    const float* dp_w1  = (const float*)d_in[2];
    const float* dp_b1  = (const float*)d_in[3];
    const float* dp_g1  = (const float*)d_in[4];
    const float* dp_be1 = (const float*)d_in[5];
    const float* dp_w2  = (const float*)d_in[6];
    const float* dp_b2  = (const float*)d_in[7];
    const float* dp_g2  = (const float*)d_in[8];
    const float* dp_be2 = (const float*)d_in[9];
    const float* dp_w3  = (const float*)d_in[10];
    const float* dp_b3  = (const float*)d_in[11];
    const float* f0_w1  = (const float*)d_in[12];
    const float* f0_b1  = (const float*)d_in[13];
    const float* f0_g1  = (const float*)d_in[14];
    const float* f0_be1 = (const float*)d_in[15];
    const float* f0_w2  = (const float*)d_in[16];
    const float* f0_b2  = (const float*)d_in[17];

    float* up   = (float*)d_out;                       // (16, 4096, 512)
    float* pdur = up + (size_t)NB * NT * IND0;         // (16, 512)
    float* pf0  = pdur + NB * NS;                      // (16, 4096)

    char* ws = (char*)d_ws;
    int*            idxarr = (int*)(ws);                          // 256 KB
    unsigned short* Bs1    = (unsigned short*)(ws + 262656);      // 768 KB
    unsigned short* Bs2    = (unsigned short*)(ws + 1049088);     // 384 KB
    unsigned short* Bsf    = (unsigned short*)(ws + 1442304);     // 768 KB
    unsigned short* h1     = (unsigned short*)(ws + 2228736);     // 4 MB
    unsigned short* emb_bf = (unsigned short*)(ws + 6423040);     // 8 MB

    prep_kernel<<<5904, 256, 0, stream>>>(emb, dur, dp_w1, dp_w2, f0_w1,
                                          emb_bf, idxarr, Bs1, Bs2, Bsf);

    // duration predictor conv1: emb_bf -> h1 (bf16)
    conv_mfma<0, 32, 512, 0, 9><<<NB * NS / 32, 256, 0, stream>>>(
        emb_bf, nullptr, Bs1, dp_b1, dp_g1, dp_be1, h1, nullptr, nullptr,
        nullptr, nullptr);
    // duration predictor conv2 + dur head: h1 -> pdur
    conv_mfma<0, 32, 256, 1, 9><<<NB * NS / 32, 256, 0, stream>>>(
        h1, nullptr, Bs2, dp_b2, dp_g2, dp_be2, nullptr, dp_w3, dp_b3,
        pdur, nullptr);
    // f0 conv + head: gather emb_bf rows via idxarr -> pf0, fused `up` write
    conv_mfma<1, 64, 512, 2, 12><<<NB * NT / 64, 256, 0, stream>>>(
        emb_bf, idxarr, Bsf, f0_b1, f0_g1, f0_be1, nullptr, f0_w2, f0_b2,
        pf0, up);
}

// Round 11
// 143.967 us; speedup vs baseline: 1.6268x; 1.0464x over previous
//
#include <hip/hip_runtime.h>
#include <math.h>

typedef __attribute__((ext_vector_type(8))) short short8;
typedef __attribute__((ext_vector_type(4))) float f32x4;
typedef __attribute__((ext_vector_type(4))) unsigned short us4;

constexpr int NB = 16, NS = 512, NT = 4096, IND0 = 512;
constexpr int UCAP = 1600;      // max uniques per batch (bound: 3*512+3)
constexpr int USTRIDE = 1604;   // ut0 row stride (ushorts)
constexpr int NCONV_F0 = 16 * 25;   // 25 unique-blocks (of 64) per batch
constexpr int NUP = 1024;           // 64 rows per up-block

__device__ __forceinline__ unsigned short f2bf(float f) {
    __bf16 h = (__bf16)f;
    return __builtin_bit_cast(unsigned short, h);
}
__device__ __forceinline__ float bf2f(unsigned short h) {
    return __uint_as_float(((unsigned)h) << 16);
}

// ---------------------------------------------------------------------------
// Merged prep kernel:
//  [0,16)      : per-batch cumsum + idx table + unique-triple scan (uid/ut0)
//  [16,2064)   : emb f32 -> bf16 cast
//  [2064,3600) : wprep dp_w1 -> Bs1   (IND=512)
//  [3600,4368) : wprep dp_w2 -> Bs2   (IND=256)
//  [4368,5904) : wprep f0_w1 -> Bsf   (IND=512)
__device__ __forceinline__ void wprep_one(const float* __restrict__ src,
                                          unsigned short* __restrict__ dst,
                                          int idx, int LOGIND) {
    int IND = 1 << LOGIND;
    int e  = idx & 7;
    int l  = (idx >> 3) & 63;
    int s  = (idx >> 9) & 1;
    int nf = (idx >> 10) & 3;
    int w  = (idx >> 12) & 3;
    int st = idx >> 14;
    int k   = st * 64 + s * 32 + ((l >> 4) << 3) + e;
    int col = w * 64 + nf * 16 + (l & 15);
    int i   = k & (IND - 1);
    int ko  = k >> LOGIND;
    dst[idx] = f2bf(src[(col * IND + i) * 3 + ko]);
}

__global__ __launch_bounds__(256)
void prep_kernel(const float* __restrict__ emb, const int* __restrict__ dur,
                 const float* __restrict__ dp_w1, const float* __restrict__ dp_w2,
                 const float* __restrict__ f0_w1,
                 unsigned short* __restrict__ emb_bf, int* __restrict__ idxarr,
                 unsigned short* __restrict__ uidg, unsigned short* __restrict__ ut0g,
                 unsigned short* __restrict__ Bs1, unsigned short* __restrict__ Bs2,
                 unsigned short* __restrict__ Bsf) {
    const int bid = blockIdx.x, t = threadIdx.x;
    if (bid < 16) {
        __shared__ int cs[NS];
        __shared__ int idxl[NT];
        __shared__ int wsum[4];
        int b = bid, w = t >> 6, lane = t & 63;
        // --- cumsum of durations ---
        int v0 = dur[b * NS + t * 2], v1 = dur[b * NS + t * 2 + 1];
        int incl = v0 + v1;
        for (int off = 1; off < 64; off <<= 1) {
            int n = __shfl_up(incl, off, 64);
            if (lane >= off) incl += n;
        }
        if (lane == 63) wsum[w] = incl;
        __syncthreads();
        int pre = 0;
        #pragma unroll
        for (int i = 0; i < 4; ++i) if (i < w) pre += wsum[i];
        incl += pre;
        cs[t * 2] = incl - v1;
        cs[t * 2 + 1] = incl;
        __syncthreads();
        int total = cs[NS - 1];
        // --- frame -> phoneme idx (-1 masked) ---
        for (int f = t; f < NT; f += 256) {
            int lo = 0, hi = NS;
            while (lo < hi) {
                int mid = (lo + hi) >> 1;
                if (cs[mid] <= f) lo = mid + 1; else hi = mid;
            }
            int v = (f < total) ? (lo < NS ? lo : NS - 1) : -1;
            idxl[f] = v;
            idxarr[b * NT + f] = v;
        }
        __syncthreads();
        // --- unique-triple scan: flag where (g(t-1),g(t),g(t+1)) changes ---
        auto gg = [&](int x) { return (x >= 0 && x < NT) ? idxl[x] : -1; };
        auto dd = [&](int x) { return gg(x) != gg(x - 1); };
        int base = t * 16, cnt = 0;
        #pragma unroll
        for (int j = 0; j < 16; ++j) {
            int f = base + j;
            bool fl = (f == 0) ? true : (dd(f - 1) || dd(f) || dd(f + 1));
            cnt += fl ? 1 : 0;
        }
        int incl2 = cnt;
        for (int off = 1; off < 64; off <<= 1) {
            int n = __shfl_up(incl2, off, 64);
            if (lane >= off) incl2 += n;
        }
        __syncthreads();
        if (lane == 63) wsum[w] = incl2;
        __syncthreads();
        int pre2 = 0;
        #pragma unroll
        for (int i = 0; i < 4; ++i) if (i < w) pre2 += wsum[i];
        int excl = pre2 + incl2 - cnt;
        #pragma unroll
        for (int j = 0; j < 16; ++j) {
            int f = base + j;
            bool fl = (f == 0) ? true : (dd(f - 1) || dd(f) || dd(f + 1));
            if (fl) { ut0g[b * USTRIDE + excl] = (unsigned short)f; excl++; }
            uidg[b * NT + f] = (unsigned short)(excl - 1);
        }
        __syncthreads();
        int tot = wsum[0] + wsum[1] + wsum[2] + wsum[3];
        for (int u = tot + t; u <= UCAP; u += 256)
            ut0g[b * USTRIDE + u] = (unsigned short)NT;
    } else if (bid < 2064) {
        int i = (bid - 16) * 256 + t;
        const float4* p = (const float4*)(emb + (size_t)i * 8);
        float4 a0 = p[0], a1 = p[1];
        short8 o;
        o[0] = (short)f2bf(a0.x); o[1] = (short)f2bf(a0.y);
        o[2] = (short)f2bf(a0.z); o[3] = (short)f2bf(a0.w);
        o[4] = (short)f2bf(a1.x); o[5] = (short)f2bf(a1.y);
        o[6] = (short)f2bf(a1.z); o[7] = (short)f2bf(a1.w);
        *(short8*)(emb_bf + (size_t)i * 8) = o;
    } else if (bid < 3600) {
        wprep_one(dp_w1, Bs1, (bid - 2064) * 256 + t, 9);
    } else if (bid < 4368) {
        wprep_one(dp_w2, Bs2, (bid - 3600) * 256 + t, 8);
    } else {
        wprep_one(f0_w1, Bsf, (bid - 4368) * 256 + t, 9);
    }
}

// ---------------------------------------------------------------------------
// Conv body (r8 structure): BM x 256, 4 waves, BK=64, A LDS dbuf (XOR-16B
// swizzle), B double register buffer. MODE 0 = dense rows (dp convs);
// MODE 2 = unique-triple rows via ut0/idxarr + epilogue pf0 scatter.
// FIN: 0 = bf16 hout; 1 = dur head exp/max1; 2 = f0 head (scatter via uid).
template<int MODE, int BM, int IND, int FIN, int LOGSL>
__device__ void conv_body(int cbid, unsigned short* smem,
                          const unsigned short* __restrict__ src,
                          const int* __restrict__ idxarr,
                          const unsigned short* __restrict__ uidg,
                          const unsigned short* __restrict__ ut0g,
                          const unsigned short* __restrict__ Bs,
                          const float* __restrict__ bias,
                          const float* __restrict__ gamma,
                          const float* __restrict__ beta,
                          unsigned short* __restrict__ hout,
                          const float* __restrict__ wfin,
                          const float* __restrict__ bfin,
                          float* __restrict__ fout) {
    constexpr int K = 3 * IND;
    constexpr int NSTEP = K / 64;
    constexpr int KOSH = (IND == 512) ? 3 : 2;
    constexpr int KOM = (IND / 64) - 1;
    constexpr int SL = 1 << LOGSL;
    constexpr int TPR = 256 / BM;
    constexpr int CH  = 8 / TPR;
    constexpr int MF  = BM / 16;
    constexpr int BUFS = BM * 64;

    const int t = threadIdx.x;
    const int w = t >> 6, l = t & 63, llo = l & 15, lhi = l >> 4;
    const int arow = t / TPR, sub = t % TPR;

    int b = 0, u0 = 0, m0 = 0;
    if (MODE == 2) { b = cbid / 25; u0 = (cbid % 25) * BM; }
    else           { m0 = cbid * BM; }

    // per-thread source rows for the 3 conv taps (-1 = zero row)
    int rid[3];
    if (MODE == 2) {
        int u = u0 + arow;
        int t0 = ut0g[b * USTRIDE + u];
        #pragma unroll
        for (int ko = 0; ko < 3; ++ko) {
            int pos = t0 + ko - 1;
            int r = -1;
            if (t0 < NT && pos >= 0 && pos < NT) {
                int ix = idxarr[b * NT + pos];
                if (ix >= 0) r = b * NS + ix;
            }
            rid[ko] = r;
        }
    } else {
        int am = m0 + arow, ab = am >> LOGSL, as_ = am & (SL - 1);
        #pragma unroll
        for (int ko = 0; ko < 3; ++ko) {
            int tr = as_ + ko - 1;
            rid[ko] = (tr >= 0 && tr < SL) ? (ab * SL + tr) : -1;
        }
    }

    f32x4 acc[MF][4];
    #pragma unroll
    for (int i = 0; i < MF; ++i)
        #pragma unroll
        for (int j = 0; j < 4; ++j) acc[i][j] = (f32x4){0.f, 0.f, 0.f, 0.f};

    short8 a[CH];
    short8 b0[8], b1[8];

    auto stageA = [&](int st) {
        int ko = st >> KOSH;
        int i0 = (st & KOM) << 6;
        int r = rid[ko];
        if (r >= 0) {
            const unsigned short* p = src + (size_t)r * IND + i0 + sub * CH * 8;
            #pragma unroll
            for (int j = 0; j < CH; ++j) a[j] = *(const short8*)(p + j * 8);
        } else {
            #pragma unroll
            for (int j = 0; j < CH; ++j) a[j] = short8{0,0,0,0,0,0,0,0};
        }
    };
    auto dsWriteA = [&](int st) {
        int buf = (st & 1) * BUFS;
        #pragma unroll
        for (int j = 0; j < CH; ++j)
            *(short8*)&smem[buf + arow * 64 + (((sub * CH + j) ^ (arow & 7)) << 3)] = a[j];
    };
    auto loadB = [&](int st, short8* bb) {
        const unsigned short* base = Bs + ((size_t)(st * 4 + w) * 8) * 512 + l * 8;
        #pragma unroll
        for (int s = 0; s < 2; ++s)
            #pragma unroll
            for (int nf = 0; nf < 4; ++nf)
                bb[s * 4 + nf] = *(const short8*)(base + (nf * 2 + s) * 512);
    };
    auto mfmaPhase = [&](int buf, short8* bc) {
        #pragma unroll
        for (int s = 0; s < 2; ++s)
            #pragma unroll
            for (int mf = 0; mf < MF; ++mf) {
                int row = mf * 16 + llo;
                short8 af = *(const short8*)&smem[buf + row * 64 +
                                                 ((((s << 2) | lhi) ^ (row & 7)) << 3)];
                #pragma unroll
                for (int nf = 0; nf < 4; ++nf)
                    acc[mf][nf] = __builtin_amdgcn_mfma_f32_16x16x32_bf16(
                        af, bc[s * 4 + nf], acc[mf][nf], 0, 0, 0);
            }
    };

    stageA(0);
    dsWriteA(0);
    stageA(1);
    loadB(0, b0);
    __syncthreads();
    for (int st = 0; st < NSTEP; st += 2) {
        loadB(st + 1, b1);
        dsWriteA(st + 1);
        if (st + 2 < NSTEP) stageA(st + 2);
        mfmaPhase(0, b0);
        __syncthreads();
        if (st + 2 < NSTEP) {
            loadB(st + 2, b0);
            dsWriteA(st + 2);
        }
        if (st + 3 < NSTEP) stageA(st + 3);
        mfmaPhase(BUFS, b1);
        __syncthreads();
    }

    // --- epilogue: bias+relu -> H tile (XOR-swizzled), LN, emit ---
    unsigned short* H = smem;
    float* f0v = (float*)(smem + BM * 256);   // disjoint scratch (MODE 2)
    #pragma unroll
    for (int nf = 0; nf < 4; ++nf) {
        int col = w * 64 + nf * 16 + llo;
        float bv = bias[col];
        #pragma unroll
        for (int mf = 0; mf < MF; ++mf)
            #pragma unroll
            for (int r = 0; r < 4; ++r) {
                int row = mf * 16 + lhi * 4 + r;
                float v = acc[mf][nf][r] + bv;
                v = v > 0.f ? v : 0.f;
                H[row * 256 + ((((col >> 2) ^ (row & 15)) << 2) | (col & 3))] = f2bf(v);
            }
    }
    __syncthreads();

    constexpr int Q = 256 / BM;
    constexpr int NG = 64 / Q;
    int row = t / Q, jj = t % Q;
    const unsigned short* Hr = H + row * 256;
    int rx = row & 15;
    float sum = 0.f, sq = 0.f;
    #pragma unroll
    for (int c4 = 0; c4 < NG; ++c4) {
        int g = jj * NG + c4;
        us4 hv = *(const us4*)&Hr[(g ^ rx) << 2];
        #pragma unroll
        for (int e = 0; e < 4; ++e) { float f = bf2f(hv[e]); sum += f; sq += f * f; }
    }
    #pragma unroll
    for (int off = Q / 2; off >= 1; off >>= 1) {
        sum += __shfl_xor(sum, off);
        sq  += __shfl_xor(sq, off);
    }
    float mean = sum * (1.f / 256.f);
    float var  = sq * (1.f / 256.f) - mean * mean;
    float rs   = rsqrtf(var + 1e-5f);

    if (FIN == 0) {
        int m = m0 + row;
        #pragma unroll
        for (int c4 = 0; c4 < NG; ++c4) {
            int g = jj * NG + c4;
            us4 hv = *(const us4*)&Hr[(g ^ rx) << 2];
            float4 gv = *(const float4*)&gamma[g * 4];
            float4 bv = *(const float4*)&beta[g * 4];
            us4 ov;
            ov[0] = f2bf((bf2f(hv[0]) - mean) * rs * gv.x + bv.x);
            ov[1] = f2bf((bf2f(hv[1]) - mean) * rs * gv.y + bv.y);
            ov[2] = f2bf((bf2f(hv[2]) - mean) * rs * gv.z + bv.z);
            ov[3] = f2bf((bf2f(hv[3]) - mean) * rs * gv.w + bv.w);
            *(us4*)&hout[(size_t)m * 256 + g * 4] = ov;
        }
    } else {
        float part = 0.f;
        #pragma unroll
        for (int c4 = 0; c4 < NG; ++c4) {
            int g = jj * NG + c4;
            us4 hv = *(const us4*)&Hr[(g ^ rx) << 2];
            float4 gv = *(const float4*)&gamma[g * 4];
            float4 bv = *(const float4*)&beta[g * 4];
            float4 wv = *(const float4*)&wfin[g * 4];
            part += ((bf2f(hv[0]) - mean) * rs * gv.x + bv.x) * wv.x;
            part += ((bf2f(hv[1]) - mean) * rs * gv.y + bv.y) * wv.y;
            part += ((bf2f(hv[2]) - mean) * rs * gv.z + bv.z) * wv.z;
            part += ((bf2f(hv[3]) - mean) * rs * gv.w + bv.w) * wv.w;
        }
        #pragma unroll
        for (int off = Q / 2; off >= 1; off >>= 1) part += __shfl_xor(part, off);
        if (FIN == 1) {
            if (jj == 0) {
                float r = part + bfin[0];
                r = expf(r); r = r > 1.f ? r : 1.f;
                fout[m0 + row] = r;
            }
        } else {   // FIN == 2: unique row value -> LDS, then scatter via uid
            if (jj == 0) f0v[row] = part + bfin[0];
            __syncthreads();
            int tstart = ut0g[b * USTRIDE + u0];
            int tend   = ut0g[b * USTRIDE + u0 + BM];
            for (int tt = tstart + t; tt < tend; tt += 256) {
                int lu = (int)uidg[b * NT + tt] - u0;
                fout[b * NT + tt] = f0v[lu];
            }
        }
    }
}

// ---------------------------------------------------------------------------
// Mega kernel: [0,400) f0 unique-conv | [400,1424) up-writer (exact f32 copy)
__global__ __launch_bounds__(256, 3)
void mega_kernel(const float* __restrict__ emb,
                 const unsigned short* __restrict__ emb_bf,
                 const int* __restrict__ idxarr,
                 const unsigned short* __restrict__ uidg,
                 const unsigned short* __restrict__ ut0g,
                 const unsigned short* __restrict__ Bsf,
                 const float* f0_b1, const float* f0_g1, const float* f0_be1,
                 const float* f0_w2, const float* f0_b2, float* pf0, float* up) {
    __shared__ unsigned short smem[64 * 256 + 128];
    int bid = blockIdx.x;
    if (bid < NCONV_F0) {
        conv_body<2, 64, 512, 2, 12>(bid, smem, emb_bf, idxarr, uidg, ut0g,
                                     Bsf, f0_b1, f0_g1, f0_be1, nullptr,
                                     f0_w2, f0_b2, pf0);
    } else {
        // up-writer: 64 frames per block, exact f32 copy of emb rows
        int* il = (int*)smem;
        int t = threadIdx.x;
        int row0 = (bid - NCONV_F0) * 64;
        if (t < 64) il[t] = idxarr[row0 + t];
        __syncthreads();
        for (int c = t; c < 64 * 128; c += 256) {
            int r = c >> 7, j = c & 127;
            int ix = il[r];
            int grow = row0 + r;
            int b = grow >> 12;
            float4 v = make_float4(0.f, 0.f, 0.f, 0.f);
            if (ix >= 0)
                v = ((const float4*)(emb + ((size_t)(b * NS + ix)) * IND0))[j];
            ((float4*)(up + (size_t)grow * IND0))[j] = v;
        }
    }
}

// ---------------------------------------------------------------------------
__global__ __launch_bounds__(256, 4)
void dp1_kernel(const unsigned short* __restrict__ emb_bf,
                const unsigned short* __restrict__ Bs1,
                const float* dp_b1, const float* dp_g1, const float* dp_be1,
                unsigned short* h1) {
    __shared__ unsigned short smem[32 * 256];
    conv_body<0, 32, 512, 0, 9>(blockIdx.x, smem, emb_bf, nullptr, nullptr,
                                nullptr, Bs1, dp_b1, dp_g1, dp_be1, h1,
                                nullptr, nullptr, nullptr);
}

__global__ __launch_bounds__(256, 4)
void dp2_kernel(const unsigned short* __restrict__ h1,
                const unsigned short* __restrict__ Bs2,
                const float* dp_b2, const float* dp_g2, const float* dp_be2,
                const float* dp_w3, const float* dp_b3, float* pdur) {
    __shared__ unsigned short smem[32 * 256];
    conv_body<0, 32, 256, 1, 9>(blockIdx.x, smem, h1, nullptr, nullptr,
                                nullptr, Bs2, dp_b2, dp_g2, dp_be2, nullptr,
                                dp_w3, dp_b3, pdur);
}

// ---------------------------------------------------------------------------
extern "C" void kernel_launch(void* const* d_in, const int* in_sizes, int n_in,
                              void* d_out, int out_size, void* d_ws, size_t ws_size,
                              hipStream_t stream) {
    const float* emb    = (const float*)d_in[0];
    const int*   dur    = (const int*)  d_in[1];
    const float* dp_w1  = (const float*)d_in[2];
    const float* dp_b1  = (const float*)d_in[3];
    const float* dp_g1  = (const float*)d_in[4];
    const float* dp_be1 = (const float*)d_in[5];
    const float* dp_w2  = (const float*)d_in[6];
    const float* dp_b2  = (const float*)d_in[7];
    const float* dp_g2  = (const float*)d_in[8];
    const float* dp_be2 = (const float*)d_in[9];
    const float* dp_w3  = (const float*)d_in[10];
    const float* dp_b3  = (const float*)d_in[11];
    const float* f0_w1  = (const float*)d_in[12];
    const float* f0_b1  = (const float*)d_in[13];
    const float* f0_g1  = (const float*)d_in[14];
    const float* f0_be1 = (const float*)d_in[15];
    const float* f0_w2  = (const float*)d_in[16];
    const float* f0_b2  = (const float*)d_in[17];

    float* up   = (float*)d_out;                       // (16, 4096, 512)
    float* pdur = up + (size_t)NB * NT * IND0;         // (16, 512)
    float* pf0  = pdur + NB * NS;                      // (16, 4096)

    char* ws = (char*)d_ws;
    int*            idxarr = (int*)(ws);                          // 256 KB
    unsigned short* uidg   = (unsigned short*)(ws + 262144);      // 128 KB
    unsigned short* ut0g   = (unsigned short*)(ws + 393216);      // ~51 KB
    unsigned short* Bs1    = (unsigned short*)(ws + 448512);      // 768 KB
    unsigned short* Bs2    = (unsigned short*)(ws + 1234944);     // 384 KB
    unsigned short* Bsf    = (unsigned short*)(ws + 1628160);     // 768 KB
    unsigned short* h1     = (unsigned short*)(ws + 2414592);     // 4 MB
    unsigned short* emb_bf = (unsigned short*)(ws + 6608896);     // 8 MB

    prep_kernel<<<5904, 256, 0, stream>>>(emb, dur, dp_w1, dp_w2, f0_w1,
                                          emb_bf, idxarr, uidg, ut0g,
                                          Bs1, Bs2, Bsf);

    // f0 unique-conv + up-writer, co-scheduled
    mega_kernel<<<NCONV_F0 + NUP, 256, 0, stream>>>(
        emb, emb_bf, idxarr, uidg, ut0g, Bsf,
        f0_b1, f0_g1, f0_be1, f0_w2, f0_b2, pf0, up);

    // duration predictor, standalone (r8-proven config)
    dp1_kernel<<<NB * NS / 32, 256, 0, stream>>>(
        emb_bf, Bs1, dp_b1, dp_g1, dp_be1, h1);
    dp2_kernel<<<NB * NS / 32, 256, 0, stream>>>(
        h1, Bs2, dp_b2, dp_g2, dp_be2, dp_w3, dp_b3, pdur);
}

// Round 12
// 121.700 us; speedup vs baseline: 1.9245x; 1.1830x over previous
//
#include <hip/hip_runtime.h>
#include <math.h>

typedef __attribute__((ext_vector_type(8))) short short8;
typedef __attribute__((ext_vector_type(4))) float f32x4;
typedef __attribute__((ext_vector_type(4))) unsigned short us4;

constexpr int NB = 16, NS = 512, NT = 4096, IND0 = 512;
constexpr int NROW = NB * NS;        // 8192 phoneme rows
constexpr int GSLAB = NROW * 256;    // elements per G slab

__device__ __forceinline__ unsigned short f2bf(float f) {
    __bf16 h = (__bf16)f;
    return __builtin_bit_cast(unsigned short, h);
}
__device__ __forceinline__ float bf2f(unsigned short h) {
    return __uint_as_float(((unsigned)h) << 16);
}

// ---------------------------------------------------------------------------
// Merged prep kernel:
//  [0,16)      : per-batch cumsum + frame->phoneme idx table
//  [16,2064)   : emb f32 -> bf16 cast
//  [2064,5136) : Wall fragments: 6 slabs (dp taps 0-2, f0 taps 0-2), K=512
//  [5136,5904) : Bs2 fragments (dp_w2, K=768)
__global__ __launch_bounds__(256)
void prep_kernel(const float* __restrict__ emb, const int* __restrict__ dur,
                 const float* __restrict__ dp_w1, const float* __restrict__ dp_w2,
                 const float* __restrict__ f0_w1,
                 unsigned short* __restrict__ emb_bf, int* __restrict__ idxarr,
                 unsigned short* __restrict__ Ball, unsigned short* __restrict__ Bs2) {
    const int bid = blockIdx.x, t = threadIdx.x;
    if (bid < 16) {
        __shared__ int cs[NS];
        __shared__ int wsum[4];
        int b = bid, w = t >> 6, lane = t & 63;
        int v0 = dur[b * NS + t * 2], v1 = dur[b * NS + t * 2 + 1];
        int incl = v0 + v1;
        for (int off = 1; off < 64; off <<= 1) {
            int n = __shfl_up(incl, off, 64);
            if (lane >= off) incl += n;
        }
        if (lane == 63) wsum[w] = incl;
        __syncthreads();
        int pre = 0;
        #pragma unroll
        for (int i = 0; i < 4; ++i) if (i < w) pre += wsum[i];
        incl += pre;
        cs[t * 2] = incl - v1;
        cs[t * 2 + 1] = incl;
        __syncthreads();
        int total = cs[NS - 1];
        for (int f = t; f < NT; f += 256) {
            int lo = 0, hi = NS;
            while (lo < hi) {
                int mid = (lo + hi) >> 1;
                if (cs[mid] <= f) lo = mid + 1; else hi = mid;
            }
            idxarr[b * NT + f] = (f < total) ? (lo < NS ? lo : NS - 1) : -1;
        }
    } else if (bid < 2064) {
        int i = (bid - 16) * 256 + t;
        const float4* p = (const float4*)(emb + (size_t)i * 8);
        float4 a0 = p[0], a1 = p[1];
        short8 o;
        o[0] = (short)f2bf(a0.x); o[1] = (short)f2bf(a0.y);
        o[2] = (short)f2bf(a0.z); o[3] = (short)f2bf(a0.w);
        o[4] = (short)f2bf(a1.x); o[5] = (short)f2bf(a1.y);
        o[6] = (short)f2bf(a1.z); o[7] = (short)f2bf(a1.w);
        *(short8*)(emb_bf + (size_t)i * 8) = o;
    } else if (bid < 5136) {
        // Wall: slab q, tap = q%3, weights = q<3 ? dp_w1 : f0_w1, K=512
        int bid2 = bid - 2064;
        int q = bid2 >> 9;                       // 512 blocks per slab
        int idx = (bid2 & 511) * 256 + t;        // [0, 131072)
        int e  = idx & 7;
        int l  = (idx >> 3) & 63;
        int s2 = (idx >> 9) & 1;
        int nf = (idx >> 10) & 3;
        int w  = (idx >> 12) & 3;
        int st = idx >> 14;                      // [0, 8)
        int k   = st * 64 + s2 * 32 + ((l >> 4) << 3) + e;   // [0,512)
        int col = w * 64 + nf * 16 + (l & 15);
        int tap = q < 3 ? q : q - 3;
        const float* srcw = q < 3 ? dp_w1 : f0_w1;
        Ball[(size_t)q * 131072 + idx] = f2bf(srcw[(col * 512 + k) * 3 + tap]);
    } else {
        // Bs2: dp_w2, K=768 (IND=256)
        int idx = (bid - 5136) * 256 + t;        // [0, 196608)
        int e  = idx & 7;
        int l  = (idx >> 3) & 63;
        int s2 = (idx >> 9) & 1;
        int nf = (idx >> 10) & 3;
        int w  = (idx >> 12) & 3;
        int st = idx >> 14;                      // [0, 12)
        int k   = st * 64 + s2 * 32 + ((l >> 4) << 3) + e;   // [0,768)
        int col = w * 64 + nf * 16 + (l & 15);
        int i   = k & 255;
        int ko  = k >> 8;
        Bs2[idx] = f2bf(dp_w2[(col * 256 + i) * 3 + ko]);
    }
}

// ---------------------------------------------------------------------------
// Big GEMM: G[q] = emb_bf (8192x512) x Wall[q] (512x256), q in [0,6).
// BM=64, 4 waves, BK=64, A LDS dbuf (XOR-16B swizzle), B reg dbuf.
// Raw bf16 store (no bias/LN) via H tile, lane-contiguous coalesced copy.
__global__ __launch_bounds__(256, 3)
void gemm_kernel(const unsigned short* __restrict__ emb_bf,
                 const unsigned short* __restrict__ Ball,
                 unsigned short* __restrict__ G) {
    constexpr int NSTEP = 8;
    constexpr int BUFS = 64 * 64;
    __shared__ unsigned short smem[64 * 256];   // union: 2 A-bufs | H tile

    const int t = threadIdx.x;
    const int q = blockIdx.x % 6;
    const int m0 = (blockIdx.x / 6) * 64;
    const int w = t >> 6, l = t & 63, llo = l & 15, lhi = l >> 4;
    const int arow = t >> 2, sub = t & 3;
    const unsigned short* Bq = Ball + (size_t)q * 131072;
    unsigned short* Gq = G + (size_t)q * GSLAB;

    f32x4 acc[4][4];
    #pragma unroll
    for (int i = 0; i < 4; ++i)
        #pragma unroll
        for (int j = 0; j < 4; ++j) acc[i][j] = (f32x4){0.f, 0.f, 0.f, 0.f};

    short8 a[2];
    short8 b0[8], b1[8];

    auto stageA = [&](int st) {
        const unsigned short* p = emb_bf + (size_t)(m0 + arow) * 512 + st * 64 + sub * 16;
        a[0] = *(const short8*)p;
        a[1] = *(const short8*)(p + 8);
    };
    auto dsWriteA = [&](int st) {
        int buf = (st & 1) * BUFS;
        *(short8*)&smem[buf + arow * 64 + (((sub * 2 + 0) ^ (arow & 7)) << 3)] = a[0];
        *(short8*)&smem[buf + arow * 64 + (((sub * 2 + 1) ^ (arow & 7)) << 3)] = a[1];
    };
    auto loadB = [&](int st, short8* bb) {
        const unsigned short* base = Bq + ((size_t)(st * 4 + w) * 8) * 512 + l * 8;
        #pragma unroll
        for (int s = 0; s < 2; ++s)
            #pragma unroll
            for (int nf = 0; nf < 4; ++nf)
                bb[s * 4 + nf] = *(const short8*)(base + (nf * 2 + s) * 512);
    };
    auto mfmaPhase = [&](int buf, short8* bc) {
        #pragma unroll
        for (int s = 0; s < 2; ++s)
            #pragma unroll
            for (int mf = 0; mf < 4; ++mf) {
                int row = mf * 16 + llo;
                short8 af = *(const short8*)&smem[buf + row * 64 +
                                                 ((((s << 2) | lhi) ^ (row & 7)) << 3)];
                #pragma unroll
                for (int nf = 0; nf < 4; ++nf)
                    acc[mf][nf] = __builtin_amdgcn_mfma_f32_16x16x32_bf16(
                        af, bc[s * 4 + nf], acc[mf][nf], 0, 0, 0);
            }
    };

    stageA(0);
    dsWriteA(0);
    stageA(1);
    loadB(0, b0);
    __syncthreads();
    for (int st = 0; st < NSTEP; st += 2) {
        loadB(st + 1, b1);
        dsWriteA(st + 1);
        if (st + 2 < NSTEP) stageA(st + 2);
        mfmaPhase(0, b0);
        __syncthreads();
        if (st + 2 < NSTEP) {
            loadB(st + 2, b0);
            dsWriteA(st + 2);
        }
        if (st + 3 < NSTEP) stageA(st + 3);
        mfmaPhase(BUFS, b1);
        __syncthreads();
    }

    // epilogue: raw acc -> H tile (XOR-swizzled bf16) -> coalesced store
    unsigned short* H = smem;
    #pragma unroll
    for (int nf = 0; nf < 4; ++nf) {
        int col = w * 64 + nf * 16 + llo;
        #pragma unroll
        for (int mf = 0; mf < 4; ++mf)
            #pragma unroll
            for (int r = 0; r < 4; ++r) {
                int row = mf * 16 + lhi * 4 + r;
                H[row * 256 + ((((col >> 2) ^ (row & 15)) << 2) | (col & 3))] =
                    f2bf(acc[mf][nf][r]);
            }
    }
    __syncthreads();
    // 64 rows x 64 us4; lane-contiguous: consecutive threads -> consecutive ch
    #pragma unroll
    for (int it = 0; it < 16; ++it) {
        int lin = it * 256 + t;
        int row = lin >> 6, g = lin & 63;
        us4 hv = *(const us4*)&H[row * 256 + ((g ^ (row & 15)) << 2)];
        *(us4*)&Gq[(size_t)(m0 + row) * 256 + g * 4] = hv;
    }
}

// ---------------------------------------------------------------------------
// Mega: up-writer (exact f32 copy) + f0 combine (sum 3 G rows + LN + head).
// 64 frames per block, 1024 blocks.
__global__ __launch_bounds__(256, 4)
void mega_kernel(const float* __restrict__ emb, const int* __restrict__ idxarr,
                 const unsigned short* __restrict__ G,
                 const float* __restrict__ f0_b1, const float* __restrict__ f0_g1,
                 const float* __restrict__ f0_be1, const float* __restrict__ f0_w2,
                 const float* __restrict__ f0_b2,
                 float* __restrict__ pf0, float* __restrict__ up) {
    __shared__ int il[66];
    const int t = threadIdx.x;
    const int row0 = blockIdx.x * 64;
    const int b = row0 >> 12, t0 = row0 & (NT - 1);

    for (int j = t; j < 66; j += 256) {
        int tf = t0 + j - 1;
        il[j] = (tf >= 0 && tf < NT) ? idxarr[b * NT + tf] : -1;
    }
    __syncthreads();

    // --- up-writer: exact f32 copy of emb rows (0 if masked) ---
    for (int c = t; c < 64 * 128; c += 256) {
        int r = c >> 7, j = c & 127;
        int ix = il[r + 1];
        float4 v = make_float4(0.f, 0.f, 0.f, 0.f);
        if (ix >= 0)
            v = ((const float4*)(emb + ((size_t)(b * NS + ix)) * IND0))[j];
        ((float4*)(up + (size_t)(row0 + r) * IND0))[j] = v;
    }

    // --- f0 combine: 4 threads per frame, 64 channels each ---
    const unsigned short* Gf = G + (size_t)3 * GSLAB;
    int r = t >> 2, jj = t & 3;
    int grow = row0 + r;
    f32x4 v[16];
    #pragma unroll
    for (int c = 0; c < 16; ++c) v[c] = (f32x4){0.f, 0.f, 0.f, 0.f};
    #pragma unroll
    for (int k = 0; k < 3; ++k) {
        int ix = il[r + k];
        if (ix >= 0) {
            const unsigned short* Gr = Gf + (size_t)k * GSLAB
                                     + (size_t)(b * NS + ix) * 256 + jj * 64;
            #pragma unroll
            for (int c = 0; c < 16; ++c) {
                us4 hv = *(const us4*)(Gr + c * 4);
                v[c][0] += bf2f(hv[0]); v[c][1] += bf2f(hv[1]);
                v[c][2] += bf2f(hv[2]); v[c][3] += bf2f(hv[3]);
            }
        }
    }
    float sum = 0.f, sq = 0.f;
    #pragma unroll
    for (int c = 0; c < 16; ++c) {
        float4 bv = *(const float4*)&f0_b1[jj * 64 + c * 4];
        #pragma unroll
        for (int e = 0; e < 4; ++e) {
            float x = v[c][e] + ((const float*)&bv)[e];
            x = x > 0.f ? x : 0.f;
            v[c][e] = x;
            sum += x; sq += x * x;
        }
    }
    sum += __shfl_xor(sum, 1); sq += __shfl_xor(sq, 1);
    sum += __shfl_xor(sum, 2); sq += __shfl_xor(sq, 2);
    float mean = sum * (1.f / 256.f);
    float rs = rsqrtf(sq * (1.f / 256.f) - mean * mean + 1e-5f);
    float part = 0.f;
    #pragma unroll
    for (int c = 0; c < 16; ++c) {
        float4 gv = *(const float4*)&f0_g1[jj * 64 + c * 4];
        float4 be = *(const float4*)&f0_be1[jj * 64 + c * 4];
        float4 wf = *(const float4*)&f0_w2[jj * 64 + c * 4];
        part += ((v[c][0] - mean) * rs * gv.x + be.x) * wf.x;
        part += ((v[c][1] - mean) * rs * gv.y + be.y) * wf.y;
        part += ((v[c][2] - mean) * rs * gv.z + be.z) * wf.z;
        part += ((v[c][3] - mean) * rs * gv.w + be.w) * wf.w;
    }
    part += __shfl_xor(part, 1);
    part += __shfl_xor(part, 2);
    if (jj == 0) pf0[grow] = part + f0_b2[0];
}

// ---------------------------------------------------------------------------
// dp1 combine: h1[m] = LN(relu(Z0[m-1]+Z1[m]+Z2[m+1] + b1)). 32 rows/block.
__global__ __launch_bounds__(256, 4)
void dp1c_kernel(const unsigned short* __restrict__ G,
                 const float* __restrict__ dp_b1, const float* __restrict__ dp_g1,
                 const float* __restrict__ dp_be1, unsigned short* __restrict__ h1) {
    const int t = threadIdx.x;
    const int m = blockIdx.x * 32 + (t >> 3);
    const int jj = t & 7;                  // 32 channels each
    const int s = m & (NS - 1);
    f32x4 v[8];
    #pragma unroll
    for (int c = 0; c < 8; ++c) v[c] = (f32x4){0.f, 0.f, 0.f, 0.f};
    #pragma unroll
    for (int k = 0; k < 3; ++k) {
        bool valid = (k == 1) || (k == 0 && s > 0) || (k == 2 && s < NS - 1);
        if (valid) {
            const unsigned short* Gr = G + (size_t)k * GSLAB
                                     + (size_t)(m + k - 1) * 256 + jj * 32;
            #pragma unroll
            for (int c = 0; c < 8; ++c) {
                us4 hv = *(const us4*)(Gr + c * 4);
                v[c][0] += bf2f(hv[0]); v[c][1] += bf2f(hv[1]);
                v[c][2] += bf2f(hv[2]); v[c][3] += bf2f(hv[3]);
            }
        }
    }
    float sum = 0.f, sq = 0.f;
    #pragma unroll
    for (int c = 0; c < 8; ++c) {
        float4 bv = *(const float4*)&dp_b1[jj * 32 + c * 4];
        #pragma unroll
        for (int e = 0; e < 4; ++e) {
            float x = v[c][e] + ((const float*)&bv)[e];
            x = x > 0.f ? x : 0.f;
            v[c][e] = x;
            sum += x; sq += x * x;
        }
    }
    #pragma unroll
    for (int off = 4; off >= 1; off >>= 1) {
        sum += __shfl_xor(sum, off);
        sq  += __shfl_xor(sq, off);
    }
    float mean = sum * (1.f / 256.f);
    float rs = rsqrtf(sq * (1.f / 256.f) - mean * mean + 1e-5f);
    #pragma unroll
    for (int c = 0; c < 8; ++c) {
        float4 gv = *(const float4*)&dp_g1[jj * 32 + c * 4];
        float4 be = *(const float4*)&dp_be1[jj * 32 + c * 4];
        us4 ov;
        ov[0] = f2bf((v[c][0] - mean) * rs * gv.x + be.x);
        ov[1] = f2bf((v[c][1] - mean) * rs * gv.y + be.y);
        ov[2] = f2bf((v[c][2] - mean) * rs * gv.z + be.z);
        ov[3] = f2bf((v[c][3] - mean) * rs * gv.w + be.w);
        *(us4*)&h1[(size_t)m * 256 + jj * 32 + c * 4] = ov;
    }
}

// ---------------------------------------------------------------------------
// dp2: conv1d(k=3)+bias+relu+LN + dur head (r11-proven body, MODE0/FIN1 only).
__global__ __launch_bounds__(256, 4)
void dp2_kernel(const unsigned short* __restrict__ src,
                const unsigned short* __restrict__ Bs,
                const float* __restrict__ bias, const float* __restrict__ gamma,
                const float* __restrict__ beta,
                const float* __restrict__ wfin, const float* __restrict__ bfin,
                float* __restrict__ fout) {
    constexpr int IND = 256, NSTEP = 12, BM = 32;
    constexpr int BUFS = BM * 64;
    __shared__ unsigned short smem[BM * 256];

    const int t = threadIdx.x;
    const int m0 = blockIdx.x * BM;
    const int w = t >> 6, l = t & 63, llo = l & 15, lhi = l >> 4;
    const int arow = t >> 3, sub = t & 7;   // TPR=8, CH=1
    const int am = m0 + arow, ab = am >> 9, as_ = am & (NS - 1);

    int rid[3];
    #pragma unroll
    for (int ko = 0; ko < 3; ++ko) {
        int tr = as_ + ko - 1;
        rid[ko] = (tr >= 0 && tr < NS) ? (ab * NS + tr) : -1;
    }

    f32x4 acc[2][4];
    #pragma unroll
    for (int i = 0; i < 2; ++i)
        #pragma unroll
        for (int j = 0; j < 4; ++j) acc[i][j] = (f32x4){0.f, 0.f, 0.f, 0.f};

    short8 a;
    short8 b0[8], b1[8];

    auto stageA = [&](int st) {
        int ko = st >> 2;
        int i0 = (st & 3) << 6;
        int r = rid[ko];
        if (r >= 0)
            a = *(const short8*)(src + (size_t)r * IND + i0 + sub * 8);
        else
            a = short8{0,0,0,0,0,0,0,0};
    };
    auto dsWriteA = [&](int st) {
        int buf = (st & 1) * BUFS;
        *(short8*)&smem[buf + arow * 64 + ((sub ^ (arow & 7)) << 3)] = a;
    };
    auto loadB = [&](int st, short8* bb) {
        const unsigned short* base = Bs + ((size_t)(st * 4 + w) * 8) * 512 + l * 8;
        #pragma unroll
        for (int s = 0; s < 2; ++s)
            #pragma unroll
            for (int nf = 0; nf < 4; ++nf)
                bb[s * 4 + nf] = *(const short8*)(base + (nf * 2 + s) * 512);
    };
    auto mfmaPhase = [&](int buf, short8* bc) {
        #pragma unroll
        for (int s = 0; s < 2; ++s)
            #pragma unroll
            for (int mf = 0; mf < 2; ++mf) {
                int row = mf * 16 + llo;
                short8 af = *(const short8*)&smem[buf + row * 64 +
                                                 ((((s << 2) | lhi) ^ (row & 7)) << 3)];
                #pragma unroll
                for (int nf = 0; nf < 4; ++nf)
                    acc[mf][nf] = __builtin_amdgcn_mfma_f32_16x16x32_bf16(
                        af, bc[s * 4 + nf], acc[mf][nf], 0, 0, 0);
            }
    };

    stageA(0);
    dsWriteA(0);
    stageA(1);
    loadB(0, b0);
    __syncthreads();
    for (int st = 0; st < NSTEP; st += 2) {
        loadB(st + 1, b1);
        dsWriteA(st + 1);
        if (st + 2 < NSTEP) stageA(st + 2);
        mfmaPhase(0, b0);
        __syncthreads();
        if (st + 2 < NSTEP) {
            loadB(st + 2, b0);
            dsWriteA(st + 2);
        }
        if (st + 3 < NSTEP) stageA(st + 3);
        mfmaPhase(BUFS, b1);
        __syncthreads();
    }

    unsigned short* H = smem;
    #pragma unroll
    for (int nf = 0; nf < 4; ++nf) {
        int col = w * 64 + nf * 16 + llo;
        float bv = bias[col];
        #pragma unroll
        for (int mf = 0; mf < 2; ++mf)
            #pragma unroll
            for (int r = 0; r < 4; ++r) {
                int row = mf * 16 + lhi * 4 + r;
                float v = acc[mf][nf][r] + bv;
                v = v > 0.f ? v : 0.f;
                H[row * 256 + ((((col >> 2) ^ (row & 15)) << 2) | (col & 3))] = f2bf(v);
            }
    }
    __syncthreads();

    int row = t >> 3, jj = t & 7;
    const unsigned short* Hr = H + row * 256;
    int rx = row & 15;
    float sum = 0.f, sq = 0.f;
    #pragma unroll
    for (int c4 = 0; c4 < 8; ++c4) {
        int g = jj * 8 + c4;
        us4 hv = *(const us4*)&Hr[(g ^ rx) << 2];
        #pragma unroll
        for (int e = 0; e < 4; ++e) { float f = bf2f(hv[e]); sum += f; sq += f * f; }
    }
    #pragma unroll
    for (int off = 4; off >= 1; off >>= 1) {
        sum += __shfl_xor(sum, off);
        sq  += __shfl_xor(sq, off);
    }
    float mean = sum * (1.f / 256.f);
    float rs = rsqrtf(sq * (1.f / 256.f) - mean * mean + 1e-5f);
    float part = 0.f;
    #pragma unroll
    for (int c4 = 0; c4 < 8; ++c4) {
        int g = jj * 8 + c4;
        us4 hv = *(const us4*)&Hr[(g ^ rx) << 2];
        float4 gv = *(const float4*)&gamma[g * 4];
        float4 bv = *(const float4*)&beta[g * 4];
        float4 wv = *(const float4*)&wfin[g * 4];
        part += ((bf2f(hv[0]) - mean) * rs * gv.x + bv.x) * wv.x;
        part += ((bf2f(hv[1]) - mean) * rs * gv.y + bv.y) * wv.y;
        part += ((bf2f(hv[2]) - mean) * rs * gv.z + bv.z) * wv.z;
        part += ((bf2f(hv[3]) - mean) * rs * gv.w + bv.w) * wv.w;
    }
    #pragma unroll
    for (int off = 4; off >= 1; off >>= 1) part += __shfl_xor(part, off);
    if (jj == 0) {
        float r = part + bfin[0];
        r = expf(r); r = r > 1.f ? r : 1.f;
        fout[m0 + row] = r;
    }
}

// ---------------------------------------------------------------------------
extern "C" void kernel_launch(void* const* d_in, const int* in_sizes, int n_in,
                              void* d_out, int out_size, void* d_ws, size_t ws_size,
                              hipStream_t stream) {
    const float* emb    = (const float*)d_in[0];
    const int*   dur    = (const int*)  d_in[1];
    const float* dp_w1  = (const float*)d_in[2];
    const float* dp_b1  = (const float*)d_in[3];
    const float* dp_g1  = (const float*)d_in[4];
    const float* dp_be1 = (const float*)d_in[5];
    const float* dp_w2  = (const float*)d_in[6];
    const float* dp_b2  = (const float*)d_in[7];
    const float* dp_g2  = (const float*)d_in[8];
    const float* dp_be2 = (const float*)d_in[9];
    const float* dp_w3  = (const float*)d_in[10];
    const float* dp_b3  = (const float*)d_in[11];
    const float* f0_w1  = (const float*)d_in[12];
    const float* f0_b1  = (const float*)d_in[13];
    const float* f0_g1  = (const float*)d_in[14];
    const float* f0_be1 = (const float*)d_in[15];
    const float* f0_w2  = (const float*)d_in[16];
    const float* f0_b2  = (const float*)d_in[17];

    float* up   = (float*)d_out;                       // (16, 4096, 512)
    float* pdur = up + (size_t)NB * NT * IND0;         // (16, 512)
    float* pf0  = pdur + NB * NS;                      // (16, 4096)

    char* ws = (char*)d_ws;
    int*            idxarr = (int*)(ws);                          // 256 KB
    unsigned short* Ball   = (unsigned short*)(ws + 262144);      // 1.5 MB
    unsigned short* Bs2    = (unsigned short*)(ws + 1835008);     // 384 KB
    unsigned short* h1     = (unsigned short*)(ws + 2228224);     // 4 MB
    unsigned short* emb_bf = (unsigned short*)(ws + 6422528);     // 8 MB
    unsigned short* G      = (unsigned short*)(ws + 14811136);    // 24 MB

    prep_kernel<<<5904, 256, 0, stream>>>(emb, dur, dp_w1, dp_w2, f0_w1,
                                          emb_bf, idxarr, Ball, Bs2);

    // G = emb_bf x [dp taps | f0 taps]  (8192 x 1536, K=512)
    gemm_kernel<<<768, 256, 0, stream>>>(emb_bf, Ball, G);

    // up-writer + f0 combine (reads G slabs 3-5)
    mega_kernel<<<NB * NT / 64, 256, 0, stream>>>(
        emb, idxarr, G, f0_b1, f0_g1, f0_be1, f0_w2, f0_b2, pf0, up);

    // dp1 combine (reads G slabs 0-2) -> h1
    dp1c_kernel<<<NROW / 32, 256, 0, stream>>>(G, dp_b1, dp_g1, dp_be1, h1);

    // dp2 conv + dur head
    dp2_kernel<<<NROW / 32, 256, 0, stream>>>(
        h1, Bs2, dp_b2, dp_g2, dp_be2, dp_w3, dp_b3, pdur);
}

// Round 13
// 119.746 us; speedup vs baseline: 1.9559x; 1.0163x over previous
//
#include <hip/hip_runtime.h>
#include <math.h>

typedef __attribute__((ext_vector_type(8))) short short8;
typedef __attribute__((ext_vector_type(4))) float f32x4;
typedef __attribute__((ext_vector_type(4))) unsigned short us4;

constexpr int NB = 16, NS = 512, NT = 4096, IND0 = 512;
constexpr int NROW = NB * NS;        // 8192 phoneme rows
constexpr int GSLAB = NROW * 256;    // elements per G slab

__device__ __forceinline__ unsigned short f2bf(float f) {
    __bf16 h = (__bf16)f;
    return __builtin_bit_cast(unsigned short, h);
}
__device__ __forceinline__ float bf2f(unsigned short h) {
    return __uint_as_float(((unsigned)h) << 16);
}

// ---------------------------------------------------------------------------
// Merged prep kernel (vectorized writers):
//  [0,16)      : per-batch cumsum + frame->phoneme idx table
//  [16,1040)   : emb f32 -> bf16 cast (2 short8 per thread)
//  [1040,1424) : Wall fragments (6 slabs: dp taps 0-2, f0 taps 0-2), short8/thread
//  [1424,1520) : Bs2 fragments (dp_w2, K=768), short8/thread
__global__ __launch_bounds__(256)
void prep_kernel(const float* __restrict__ emb, const int* __restrict__ dur,
                 const float* __restrict__ dp_w1, const float* __restrict__ dp_w2,
                 const float* __restrict__ f0_w1,
                 unsigned short* __restrict__ emb_bf, int* __restrict__ idxarr,
                 unsigned short* __restrict__ Ball, unsigned short* __restrict__ Bs2) {
    const int bid = blockIdx.x, t = threadIdx.x;
    if (bid < 16) {
        __shared__ int cs[NS];
        __shared__ int wsum[4];
        int b = bid, w = t >> 6, lane = t & 63;
        int v0 = dur[b * NS + t * 2], v1 = dur[b * NS + t * 2 + 1];
        int incl = v0 + v1;
        for (int off = 1; off < 64; off <<= 1) {
            int n = __shfl_up(incl, off, 64);
            if (lane >= off) incl += n;
        }
        if (lane == 63) wsum[w] = incl;
        __syncthreads();
        int pre = 0;
        #pragma unroll
        for (int i = 0; i < 4; ++i) if (i < w) pre += wsum[i];
        incl += pre;
        cs[t * 2] = incl - v1;
        cs[t * 2 + 1] = incl;
        __syncthreads();
        int total = cs[NS - 1];
        for (int f = t; f < NT; f += 256) {
            int lo = 0, hi = NS;
            while (lo < hi) {
                int mid = (lo + hi) >> 1;
                if (cs[mid] <= f) lo = mid + 1; else hi = mid;
            }
            idxarr[b * NT + f] = (f < total) ? (lo < NS ? lo : NS - 1) : -1;
        }
    } else if (bid < 1040) {
        int i0 = (bid - 16) * 256 + t;     // short8 index; 2 per thread
        #pragma unroll
        for (int rep = 0; rep < 2; ++rep) {
            int i = i0 + rep * 262144;
            const float4* p = (const float4*)(emb + (size_t)i * 8);
            float4 a0 = p[0], a1 = p[1];
            short8 o;
            o[0] = (short)f2bf(a0.x); o[1] = (short)f2bf(a0.y);
            o[2] = (short)f2bf(a0.z); o[3] = (short)f2bf(a0.w);
            o[4] = (short)f2bf(a1.x); o[5] = (short)f2bf(a1.y);
            o[6] = (short)f2bf(a1.z); o[7] = (short)f2bf(a1.w);
            *(short8*)(emb_bf + (size_t)i * 8) = o;
        }
    } else if (bid < 1424) {
        // Wall: gidx8 in [0, 6*16384); slab q, 16384 short8 each
        int gidx8 = (bid - 1040) * 256 + t;
        int q = gidx8 >> 14;
        int r8 = gidx8 & 16383;
        int l  = r8 & 63;
        int s2 = (r8 >> 6) & 1;
        int nf = (r8 >> 7) & 3;
        int w  = (r8 >> 9) & 3;
        int st = r8 >> 11;                  // [0,8)
        int k0  = st * 64 + s2 * 32 + ((l >> 4) << 3);
        int col = w * 64 + nf * 16 + (l & 15);
        int tap = q < 3 ? q : q - 3;
        const float* srcw = q < 3 ? dp_w1 : f0_w1;
        const float* sp = srcw + (size_t)(col * 512 + k0) * 3 + tap;
        short8 o;
        #pragma unroll
        for (int e = 0; e < 8; ++e) o[e] = (short)f2bf(sp[e * 3]);
        *(short8*)(Ball + (size_t)q * 131072 + (size_t)r8 * 8) = o;
    } else {
        // Bs2: gidx8 in [0, 24576)
        int r8 = (bid - 1424) * 256 + t;
        int l  = r8 & 63;
        int s2 = (r8 >> 6) & 1;
        int nf = (r8 >> 7) & 3;
        int w  = (r8 >> 9) & 3;
        int st = r8 >> 11;                  // [0,12)
        int k0  = st * 64 + s2 * 32 + ((l >> 4) << 3);
        int col = w * 64 + nf * 16 + (l & 15);
        int i0  = k0 & 255;
        int ko  = k0 >> 8;
        const float* sp = dp_w2 + (size_t)(col * 256 + i0) * 3 + ko;
        short8 o;
        #pragma unroll
        for (int e = 0; e < 8; ++e) o[e] = (short)f2bf(sp[e * 3]);
        *(short8*)(Bs2 + (size_t)r8 * 8) = o;
    }
}

// ---------------------------------------------------------------------------
// Big GEMM: G[q] = emb_bf (8192x512) x Wall[q] (512x256), q in [0,6).
// BM=64, 4 waves, BK=64, A LDS dbuf (XOR-16B swizzle), B reg dbuf.
__global__ __launch_bounds__(256, 3)
void gemm_kernel(const unsigned short* __restrict__ emb_bf,
                 const unsigned short* __restrict__ Ball,
                 unsigned short* __restrict__ G) {
    constexpr int NSTEP = 8;
    constexpr int BUFS = 64 * 64;
    __shared__ unsigned short smem[64 * 256];   // union: 2 A-bufs | H tile

    const int t = threadIdx.x;
    const int q = blockIdx.x % 6;
    const int m0 = (blockIdx.x / 6) * 64;
    const int w = t >> 6, l = t & 63, llo = l & 15, lhi = l >> 4;
    const int arow = t >> 2, sub = t & 3;
    const unsigned short* Bq = Ball + (size_t)q * 131072;
    unsigned short* Gq = G + (size_t)q * GSLAB;

    f32x4 acc[4][4];
    #pragma unroll
    for (int i = 0; i < 4; ++i)
        #pragma unroll
        for (int j = 0; j < 4; ++j) acc[i][j] = (f32x4){0.f, 0.f, 0.f, 0.f};

    short8 a[2];
    short8 b0[8], b1[8];

    auto stageA = [&](int st) {
        const unsigned short* p = emb_bf + (size_t)(m0 + arow) * 512 + st * 64 + sub * 16;
        a[0] = *(const short8*)p;
        a[1] = *(const short8*)(p + 8);
    };
    auto dsWriteA = [&](int st) {
        int buf = (st & 1) * BUFS;
        *(short8*)&smem[buf + arow * 64 + (((sub * 2 + 0) ^ (arow & 7)) << 3)] = a[0];
        *(short8*)&smem[buf + arow * 64 + (((sub * 2 + 1) ^ (arow & 7)) << 3)] = a[1];
    };
    auto loadB = [&](int st, short8* bb) {
        const unsigned short* base = Bq + ((size_t)(st * 4 + w) * 8) * 512 + l * 8;
        #pragma unroll
        for (int s = 0; s < 2; ++s)
            #pragma unroll
            for (int nf = 0; nf < 4; ++nf)
                bb[s * 4 + nf] = *(const short8*)(base + (nf * 2 + s) * 512);
    };
    auto mfmaPhase = [&](int buf, short8* bc) {
        #pragma unroll
        for (int s = 0; s < 2; ++s)
            #pragma unroll
            for (int mf = 0; mf < 4; ++mf) {
                int row = mf * 16 + llo;
                short8 af = *(const short8*)&smem[buf + row * 64 +
                                                 ((((s << 2) | lhi) ^ (row & 7)) << 3)];
                #pragma unroll
                for (int nf = 0; nf < 4; ++nf)
                    acc[mf][nf] = __builtin_amdgcn_mfma_f32_16x16x32_bf16(
                        af, bc[s * 4 + nf], acc[mf][nf], 0, 0, 0);
            }
    };

    stageA(0);
    dsWriteA(0);
    stageA(1);
    loadB(0, b0);
    __syncthreads();
    for (int st = 0; st < NSTEP; st += 2) {
        loadB(st + 1, b1);
        dsWriteA(st + 1);
        if (st + 2 < NSTEP) stageA(st + 2);
        mfmaPhase(0, b0);
        __syncthreads();
        if (st + 2 < NSTEP) {
            loadB(st + 2, b0);
            dsWriteA(st + 2);
        }
        if (st + 3 < NSTEP) stageA(st + 3);
        mfmaPhase(BUFS, b1);
        __syncthreads();
    }

    // epilogue: raw acc -> H tile (XOR-swizzled bf16) -> coalesced store
    unsigned short* H = smem;
    #pragma unroll
    for (int nf = 0; nf < 4; ++nf) {
        int col = w * 64 + nf * 16 + llo;
        #pragma unroll
        for (int mf = 0; mf < 4; ++mf)
            #pragma unroll
            for (int r = 0; r < 4; ++r) {
                int row = mf * 16 + lhi * 4 + r;
                H[row * 256 + ((((col >> 2) ^ (row & 15)) << 2) | (col & 3))] =
                    f2bf(acc[mf][nf][r]);
            }
    }
    __syncthreads();
    #pragma unroll
    for (int it = 0; it < 16; ++it) {
        int lin = it * 256 + t;
        int row = lin >> 6, g = lin & 63;
        us4 hv = *(const us4*)&H[row * 256 + ((g ^ (row & 15)) << 2)];
        *(us4*)&Gq[(size_t)(m0 + row) * 256 + g * 4] = hv;
    }
}

// ---------------------------------------------------------------------------
// Mega: up-writer (exact f32 copy) + f0 combine (sum 3 G rows + LN + head).
__global__ __launch_bounds__(256, 4)
void mega_kernel(const float* __restrict__ emb, const int* __restrict__ idxarr,
                 const unsigned short* __restrict__ G,
                 const float* __restrict__ f0_b1, const float* __restrict__ f0_g1,
                 const float* __restrict__ f0_be1, const float* __restrict__ f0_w2,
                 const float* __restrict__ f0_b2,
                 float* __restrict__ pf0, float* __restrict__ up) {
    __shared__ int il[66];
    const int t = threadIdx.x;
    const int row0 = blockIdx.x * 64;
    const int b = row0 >> 12, t0 = row0 & (NT - 1);

    for (int j = t; j < 66; j += 256) {
        int tf = t0 + j - 1;
        il[j] = (tf >= 0 && tf < NT) ? idxarr[b * NT + tf] : -1;
    }
    __syncthreads();

    for (int c = t; c < 64 * 128; c += 256) {
        int r = c >> 7, j = c & 127;
        int ix = il[r + 1];
        float4 v = make_float4(0.f, 0.f, 0.f, 0.f);
        if (ix >= 0)
            v = ((const float4*)(emb + ((size_t)(b * NS + ix)) * IND0))[j];
        ((float4*)(up + (size_t)(row0 + r) * IND0))[j] = v;
    }

    const unsigned short* Gf = G + (size_t)3 * GSLAB;
    int r = t >> 2, jj = t & 3;
    int grow = row0 + r;
    f32x4 v[16];
    #pragma unroll
    for (int c = 0; c < 16; ++c) v[c] = (f32x4){0.f, 0.f, 0.f, 0.f};
    #pragma unroll
    for (int k = 0; k < 3; ++k) {
        int ix = il[r + k];
        if (ix >= 0) {
            const unsigned short* Gr = Gf + (size_t)k * GSLAB
                                     + (size_t)(b * NS + ix) * 256 + jj * 64;
            #pragma unroll
            for (int c = 0; c < 16; ++c) {
                us4 hv = *(const us4*)(Gr + c * 4);
                v[c][0] += bf2f(hv[0]); v[c][1] += bf2f(hv[1]);
                v[c][2] += bf2f(hv[2]); v[c][3] += bf2f(hv[3]);
            }
        }
    }
    float sum = 0.f, sq = 0.f;
    #pragma unroll
    for (int c = 0; c < 16; ++c) {
        float4 bv = *(const float4*)&f0_b1[jj * 64 + c * 4];
        #pragma unroll
        for (int e = 0; e < 4; ++e) {
            float x = v[c][e] + ((const float*)&bv)[e];
            x = x > 0.f ? x : 0.f;
            v[c][e] = x;
            sum += x; sq += x * x;
        }
    }
    sum += __shfl_xor(sum, 1); sq += __shfl_xor(sq, 1);
    sum += __shfl_xor(sum, 2); sq += __shfl_xor(sq, 2);
    float mean = sum * (1.f / 256.f);
    float rs = rsqrtf(sq * (1.f / 256.f) - mean * mean + 1e-5f);
    float part = 0.f;
    #pragma unroll
    for (int c = 0; c < 16; ++c) {
        float4 gv = *(const float4*)&f0_g1[jj * 64 + c * 4];
        float4 be = *(const float4*)&f0_be1[jj * 64 + c * 4];
        float4 wf = *(const float4*)&f0_w2[jj * 64 + c * 4];
        part += ((v[c][0] - mean) * rs * gv.x + be.x) * wf.x;
        part += ((v[c][1] - mean) * rs * gv.y + be.y) * wf.y;
        part += ((v[c][2] - mean) * rs * gv.z + be.z) * wf.z;
        part += ((v[c][3] - mean) * rs * gv.w + be.w) * wf.w;
    }
    part += __shfl_xor(part, 1);
    part += __shfl_xor(part, 2);
    if (jj == 0) pf0[grow] = part + f0_b2[0];
}

// ---------------------------------------------------------------------------
// Fused dp chain: build 34 h1 rows in LDS from G slabs 0-2 (combine+LN),
// one barrier, then barrier-free K loop (A-resident, B reg ping-pong) +
// LN + dur head. 32 output rows per block.
__global__ __launch_bounds__(256, 4)
void dpf_kernel(const unsigned short* __restrict__ G,
                const float* __restrict__ dp_b1, const float* __restrict__ dp_g1,
                const float* __restrict__ dp_be1,
                const unsigned short* __restrict__ Bs2,
                const float* __restrict__ bias2, const float* __restrict__ gamma2,
                const float* __restrict__ beta2,
                const float* __restrict__ wfin, const float* __restrict__ bfin,
                float* __restrict__ pdur) {
    constexpr int NSTEP = 12;
    __shared__ unsigned short A[34 * 256];
    __shared__ unsigned short H[32 * 256];

    const int t = threadIdx.x;
    const int m0 = blockIdx.x * 32;
    const int w = t >> 6, l = t & 63, llo = l & 15, lhi = l >> 4;

    // --- build h1 table: A[j] = h1[m0-1+j], j in [0,34); zero if pad row ---
    {
        int sub = t & 7;
        for (int j = t >> 3; j < 34; j += 32) {
            int sm = (m0 & (NS - 1)) - 1 + j;
            bool rowv = (sm >= 0 && sm < NS);
            int m = m0 - 1 + j;
            f32x4 v[8];
            #pragma unroll
            for (int c = 0; c < 8; ++c) v[c] = (f32x4){0.f, 0.f, 0.f, 0.f};
            if (rowv) {
                #pragma unroll
                for (int k = 0; k < 3; ++k) {
                    int sp = sm + k - 1;
                    if (sp >= 0 && sp < NS) {
                        const unsigned short* Gr = G + (size_t)k * GSLAB
                                                 + (size_t)(m + k - 1) * 256 + sub * 32;
                        #pragma unroll
                        for (int c = 0; c < 8; ++c) {
                            us4 hv = *(const us4*)(Gr + c * 4);
                            v[c][0] += bf2f(hv[0]); v[c][1] += bf2f(hv[1]);
                            v[c][2] += bf2f(hv[2]); v[c][3] += bf2f(hv[3]);
                        }
                    }
                }
            }
            float sum = 0.f, sq = 0.f;
            #pragma unroll
            for (int c = 0; c < 8; ++c) {
                float4 bv = *(const float4*)&dp_b1[sub * 32 + c * 4];
                #pragma unroll
                for (int e = 0; e < 4; ++e) {
                    float x = v[c][e] + ((const float*)&bv)[e];
                    x = x > 0.f ? x : 0.f;
                    v[c][e] = x; sum += x; sq += x * x;
                }
            }
            #pragma unroll
            for (int off = 4; off >= 1; off >>= 1) {
                sum += __shfl_xor(sum, off);
                sq  += __shfl_xor(sq, off);
            }
            float mean = sum * (1.f / 256.f);
            float rs = rsqrtf(sq * (1.f / 256.f) - mean * mean + 1e-5f);
            #pragma unroll
            for (int cc = 0; cc < 4; ++cc) {
                int ch = sub * 4 + cc;
                float4 g0 = *(const float4*)&dp_g1[ch * 8];
                float4 g1 = *(const float4*)&dp_g1[ch * 8 + 4];
                float4 e0 = *(const float4*)&dp_be1[ch * 8];
                float4 e1 = *(const float4*)&dp_be1[ch * 8 + 4];
                short8 o;
                if (rowv) {
                    f32x4 lo = v[cc * 2], hi = v[cc * 2 + 1];
                    o[0] = (short)f2bf((lo[0] - mean) * rs * g0.x + e0.x);
                    o[1] = (short)f2bf((lo[1] - mean) * rs * g0.y + e0.y);
                    o[2] = (short)f2bf((lo[2] - mean) * rs * g0.z + e0.z);
                    o[3] = (short)f2bf((lo[3] - mean) * rs * g0.w + e0.w);
                    o[4] = (short)f2bf((hi[0] - mean) * rs * g1.x + e1.x);
                    o[5] = (short)f2bf((hi[1] - mean) * rs * g1.y + e1.y);
                    o[6] = (short)f2bf((hi[2] - mean) * rs * g1.z + e1.z);
                    o[7] = (short)f2bf((hi[3] - mean) * rs * g1.w + e1.w);
                } else {
                    o = short8{0,0,0,0,0,0,0,0};
                }
                *(short8*)&A[j * 256 + ((ch ^ (j & 7)) << 3)] = o;
            }
        }
    }
    __syncthreads();

    f32x4 acc[2][4];
    #pragma unroll
    for (int i = 0; i < 2; ++i)
        #pragma unroll
        for (int j = 0; j < 4; ++j) acc[i][j] = (f32x4){0.f, 0.f, 0.f, 0.f};

    short8 b0[8], b1[8];
    auto loadB = [&](int st, short8* bb) {
        const unsigned short* base = Bs2 + ((size_t)(st * 4 + w) * 8) * 512 + l * 8;
        #pragma unroll
        for (int s = 0; s < 2; ++s)
            #pragma unroll
            for (int nf = 0; nf < 4; ++nf)
                bb[s * 4 + nf] = *(const short8*)(base + (nf * 2 + s) * 512);
    };
    auto mfmaPhase = [&](int st, short8* bc) {
        int ko = st >> 2;
        int cb = (st & 3) << 3;
        #pragma unroll
        for (int s = 0; s < 2; ++s)
            #pragma unroll
            for (int mf = 0; mf < 2; ++mf) {
                int jr = mf * 16 + llo + ko;
                int ch = cb + ((s << 2) | lhi);
                short8 af = *(const short8*)&A[jr * 256 + ((ch ^ (jr & 7)) << 3)];
                #pragma unroll
                for (int nf = 0; nf < 4; ++nf)
                    acc[mf][nf] = __builtin_amdgcn_mfma_f32_16x16x32_bf16(
                        af, bc[s * 4 + nf], acc[mf][nf], 0, 0, 0);
            }
    };

    // barrier-free K loop (A resident in LDS)
    loadB(0, b0);
    for (int st = 0; st < NSTEP; st += 2) {
        loadB(st + 1, b1);
        mfmaPhase(st, b0);
        if (st + 2 < NSTEP) loadB(st + 2, b0);
        mfmaPhase(st + 1, b1);
    }

    // --- epilogue: bias+relu -> H, LN, dur head ---
    #pragma unroll
    for (int nf = 0; nf < 4; ++nf) {
        int col = w * 64 + nf * 16 + llo;
        float bv = bias2[col];
        #pragma unroll
        for (int mf = 0; mf < 2; ++mf)
            #pragma unroll
            for (int r = 0; r < 4; ++r) {
                int row = mf * 16 + lhi * 4 + r;
                float x = acc[mf][nf][r] + bv;
                x = x > 0.f ? x : 0.f;
                H[row * 256 + ((((col >> 2) ^ (row & 15)) << 2) | (col & 3))] = f2bf(x);
            }
    }
    __syncthreads();

    int row = t >> 3, jj = t & 7;
    const unsigned short* Hr = H + row * 256;
    int rx = row & 15;
    float sum = 0.f, sq = 0.f;
    #pragma unroll
    for (int c4 = 0; c4 < 8; ++c4) {
        int g = jj * 8 + c4;
        us4 hv = *(const us4*)&Hr[(g ^ rx) << 2];
        #pragma unroll
        for (int e = 0; e < 4; ++e) { float f = bf2f(hv[e]); sum += f; sq += f * f; }
    }
    #pragma unroll
    for (int off = 4; off >= 1; off >>= 1) {
        sum += __shfl_xor(sum, off);
        sq  += __shfl_xor(sq, off);
    }
    float mean = sum * (1.f / 256.f);
    float rs = rsqrtf(sq * (1.f / 256.f) - mean * mean + 1e-5f);
    float part = 0.f;
    #pragma unroll
    for (int c4 = 0; c4 < 8; ++c4) {
        int g = jj * 8 + c4;
        us4 hv = *(const us4*)&Hr[(g ^ rx) << 2];
        float4 gv = *(const float4*)&gamma2[g * 4];
        float4 bv = *(const float4*)&beta2[g * 4];
        float4 wv = *(const float4*)&wfin[g * 4];
        part += ((bf2f(hv[0]) - mean) * rs * gv.x + bv.x) * wv.x;
        part += ((bf2f(hv[1]) - mean) * rs * gv.y + bv.y) * wv.y;
        part += ((bf2f(hv[2]) - mean) * rs * gv.z + bv.z) * wv.z;
        part += ((bf2f(hv[3]) - mean) * rs * gv.w + bv.w) * wv.w;
    }
    #pragma unroll
    for (int off = 4; off >= 1; off >>= 1) part += __shfl_xor(part, off);
    if (jj == 0) {
        float r = part + bfin[0];
        r = expf(r); r = r > 1.f ? r : 1.f;
        pdur[m0 + row] = r;
    }
}

// ---------------------------------------------------------------------------
extern "C" void kernel_launch(void* const* d_in, const int* in_sizes, int n_in,
                              void* d_out, int out_size, void* d_ws, size_t ws_size,
                              hipStream_t stream) {
    const float* emb    = (const float*)d_in[0];
    const int*   dur    = (const int*)  d_in[1];
    const float* dp_w1  = (const float*)d_in[2];
    const float* dp_b1  = (const float*)d_in[3];
    const float* dp_g1  = (const float*)d_in[4];
    const float* dp_be1 = (const float*)d_in[5];
    const float* dp_w2  = (const float*)d_in[6];
    const float* dp_b2  = (const float*)d_in[7];
    const float* dp_g2  = (const float*)d_in[8];
    const float* dp_be2 = (const float*)d_in[9];
    const float* dp_w3  = (const float*)d_in[10];
    const float* dp_b3  = (const float*)d_in[11];
    const float* f0_w1  = (const float*)d_in[12];
    const float* f0_b1  = (const float*)d_in[13];
    const float* f0_g1  = (const float*)d_in[14];
    const float* f0_be1 = (const float*)d_in[15];
    const float* f0_w2  = (const float*)d_in[16];
    const float* f0_b2  = (const float*)d_in[17];

    float* up   = (float*)d_out;                       // (16, 4096, 512)
    float* pdur = up + (size_t)NB * NT * IND0;         // (16, 512)
    float* pf0  = pdur + NB * NS;                      // (16, 4096)

    char* ws = (char*)d_ws;
    int*            idxarr = (int*)(ws);                          // 256 KB
    unsigned short* Ball   = (unsigned short*)(ws + 262144);      // 1.5 MB
    unsigned short* Bs2    = (unsigned short*)(ws + 1835008);     // 384 KB
    unsigned short* emb_bf = (unsigned short*)(ws + 6422528);     // 8 MB
    unsigned short* G      = (unsigned short*)(ws + 14811136);    // 24 MB

    prep_kernel<<<1520, 256, 0, stream>>>(emb, dur, dp_w1, dp_w2, f0_w1,
                                          emb_bf, idxarr, Ball, Bs2);

    // G = emb_bf x [dp taps | f0 taps]  (8192 x 1536, K=512)
    gemm_kernel<<<768, 256, 0, stream>>>(emb_bf, Ball, G);

    // up-writer + f0 combine (reads G slabs 3-5)
    mega_kernel<<<NB * NT / 64, 256, 0, stream>>>(
        emb, idxarr, G, f0_b1, f0_g1, f0_be1, f0_w2, f0_b2, pf0, up);

    // fused dp chain (reads G slabs 0-2) -> pdur
    dpf_kernel<<<NROW / 32, 256, 0, stream>>>(
        G, dp_b1, dp_g1, dp_be1, Bs2, dp_b2, dp_g2, dp_be2,
        dp_w3, dp_b3, pdur);
}